// Round 6
// baseline (350.423 us; speedup 1.0000x reference)
//
#include <hip/hip_runtime.h>
#include <hip/hip_bf16.h>

typedef unsigned short u16;
typedef unsigned int u32;
typedef u16 u16x8 __attribute__((ext_vector_type(8)));
typedef __bf16 bf16x8 __attribute__((ext_vector_type(8)));
typedef float f32x4 __attribute__((ext_vector_type(4)));

#define B_SZ 2
#define T_SZ 2048
#define DMODEL 1024
#define DINNER 2048
#define DSTATE 128
#define NHEADS 32
#define HEADDIM 64
#define CONVDIM 2304
#define DINPROJ 4384
#define DINPROJ_P 4480        // padded to 35*128 for GEMM1 tiles
#define NROWS (B_SZ * T_SZ)   // 4096
#define L_CH 128
#define NCH 16                // chunks per batch (T/L)

__device__ __forceinline__ float bf2f(u16 u) {
    union { float f; u32 i; } v; v.i = ((u32)u) << 16; return v.f;
}
__device__ __forceinline__ u16 f2bf(float f) {
    union { float f; u32 i; } v; v.f = f;
    u32 r = v.i + 0x7FFFu + ((v.i >> 16) & 1u);
    return (u16)(r >> 16);
}
__device__ __forceinline__ bf16x8 ldfrag(const u16* p) {
    return __builtin_bit_cast(bf16x8, *(const u16x8*)p);
}
__device__ __forceinline__ void gload_lds16(const u16* g, u16* l) {
    __builtin_amdgcn_global_load_lds(
        (const __attribute__((address_space(1))) unsigned int*)g,
        (__attribute__((address_space(3))) unsigned int*)l, 16, 0, 0);
}

// ---------------- transpose + f32->bf16: out[n][k] = in[k][n] ----------------
__global__ __launch_bounds__(256) void trans_kernel(
    const float* __restrict__ in, u16* __restrict__ out, int K, int N)
{
    __shared__ u16 tile[64][66];
    const int n0 = blockIdx.x * 64, k0 = blockIdx.y * 64;
    const int tid = threadIdx.x;
#pragma unroll
    for (int r = 0; r < 16; r++) {
        int idx = r * 256 + tid;
        int k = idx >> 6, n = idx & 63;
        float v = (n0 + n < N) ? in[(size_t)(k0 + k) * N + n0 + n] : 0.f;
        tile[n][k] = f2bf(v);
    }
    __syncthreads();
#pragma unroll
    for (int r = 0; r < 16; r++) {
        int idx = r * 256 + tid;
        int n = idx >> 6, k = idx & 63;
        out[(size_t)(n0 + n) * K + k0 + k] = tile[n][k];
    }
}

// ---------------- RMSNorm on input (D=1024), f32 in -> bf16 out ----------------
__global__ __launch_bounds__(256) void rmsnorm_in_kernel(
    const float* __restrict__ x, const float* __restrict__ w, u16* __restrict__ out)
{
    const int row = blockIdx.x;
    const float* xr = x + (size_t)row * DMODEL;
    float vals[4]; float ss = 0.f;
#pragma unroll
    for (int i = 0; i < 4; i++) {
        int c = threadIdx.x + i * 256;
        float v = xr[c]; vals[i] = v; ss += v * v;
    }
#pragma unroll
    for (int o = 32; o; o >>= 1) ss += __shfl_xor(ss, o);
    __shared__ float red[4];
    if ((threadIdx.x & 63) == 0) red[threadIdx.x >> 6] = ss;
    __syncthreads();
    ss = red[0] + red[1] + red[2] + red[3];
    float sc = rsqrtf(ss / (float)DMODEL + 1e-5f);
#pragma unroll
    for (int i = 0; i < 4; i++) {
        int c = threadIdx.x + i * 256;
        out[(size_t)row * DMODEL + c] = f2bf(vals[i] * sc * w[c]);
    }
}

// ---------------- 128x128 bf16 MFMA GEMM, BK=64, XOR-swizzled, compile-time K ----------------
// A [M][KC] bf16, BT [NP][KC] bf16 (zero-padded rows). 1D grid, supertile-8 on M.
// MODE 0: bf16 out; MODE 1: f32 out + f32 residual.
template<int MODE, int KC>
__global__ __launch_bounds__(256) void gemm128_kernel(
    const u16* __restrict__ A, const u16* __restrict__ BT, void* __restrict__ Cv,
    const float* __restrict__ Res, int Nst, int nbx)
{
    __shared__ u16 As[128 * 64];   // 16 KB, unpadded rows of 64 u16 (128 B)
    __shared__ u16 Bs[128 * 64];   // 16 KB
    const int tid = threadIdx.x;
    const int l = tid & 63, w = tid >> 6;
    const int per = nbx * 8;
    const int grp = blockIdx.x / per, r = blockIdx.x % per;
    const int m0 = (grp * 8 + (r & 7)) * 128;
    const int n0 = (r >> 3) * 128;
    const int ml = l & 15, quad = l >> 4;
    const int wm = (w & 1) * 64, wn = (w >> 1) * 64;
    f32x4 acc[4][4] = {};
    const int srow = l >> 3;
    const int sgx = (l & 7) ^ srow;
    const u16* Ag = A + (size_t)(m0 + w * 8 + srow) * KC + sgx * 8;
    const u16* Bg = BT + (size_t)(n0 + w * 8 + srow) * KC + sgx * 8;
    u16* const As_w = &As[(w * 8) * 64];
    u16* const Bs_w = &Bs[(w * 8) * 64];

#pragma unroll 4
    for (int k0 = 0; k0 < KC; k0 += 64) {
        __syncthreads();
#pragma unroll
        for (int j = 0; j < 4; j++) {
            gload_lds16(Ag + (size_t)(j * 32) * KC + k0, As_w + j * 32 * 64);
            gload_lds16(Bg + (size_t)(j * 32) * KC + k0, Bs_w + j * 32 * 64);
        }
        __syncthreads();
#pragma unroll
        for (int ks4 = 0; ks4 < 2; ks4++) {
            bf16x8 af[4], bfr[4];
#pragma unroll
            for (int i = 0; i < 4; i++)
                af[i] = ldfrag(&As[(wm + i * 16 + ml) * 64 +
                                   (((ks4 * 4 + quad) ^ (ml & 7)) * 8)]);
#pragma unroll
            for (int i = 0; i < 4; i++)
                bfr[i] = ldfrag(&Bs[(wn + i * 16 + ml) * 64 +
                                    (((ks4 * 4 + quad) ^ (ml & 7)) * 8)]);
#pragma unroll
            for (int mt = 0; mt < 4; mt++)
#pragma unroll
                for (int nt = 0; nt < 4; nt++)
                    acc[mt][nt] = __builtin_amdgcn_mfma_f32_16x16x32_bf16(
                        af[mt], bfr[nt], acc[mt][nt], 0, 0, 0);
        }
    }
#pragma unroll
    for (int mt = 0; mt < 4; mt++)
#pragma unroll
        for (int nt = 0; nt < 4; nt++)
#pragma unroll
            for (int rg = 0; rg < 4; rg++) {
                int m = m0 + wm + mt * 16 + quad * 4 + rg;
                int n = n0 + wn + nt * 16 + ml;
                if (n < Nst) {
                    if (MODE == 0)
                        ((u16*)Cv)[(size_t)m * Nst + n] = f2bf(acc[mt][nt][rg]);
                    else
                        ((float*)Cv)[(size_t)m * Nst + n] =
                            acc[mt][nt][rg] + Res[(size_t)m * Nst + n];
                }
            }
}

// ---------------- 128(M)x64(N) bf16 MFMA GEMM, BK=64, swizzled, compile-time K ----------------
template<int KC>
__global__ __launch_bounds__(256) void gemm128x64_kernel(
    const u16* __restrict__ A, const u16* __restrict__ BT, float* __restrict__ C,
    const float* __restrict__ Res, int Nst, int nbx)
{
    __shared__ u16 As[128 * 64];   // 16 KB
    __shared__ u16 Bs[64 * 64];    //  8 KB
    const int tid = threadIdx.x;
    const int l = tid & 63, w = tid >> 6;
    const int per = nbx * 8;
    const int grp = blockIdx.x / per, r = blockIdx.x % per;
    const int m0 = (grp * 8 + (r & 7)) * 128;
    const int n0 = (r >> 3) * 64;
    const int ml = l & 15, quad = l >> 4;
    const int wm = w * 32;
    f32x4 acc[2][4] = {};
    const int srow = l >> 3;
    const int sgx = (l & 7) ^ srow;
    const u16* Ag = A + (size_t)(m0 + w * 8 + srow) * KC + sgx * 8;
    const u16* Bg = BT + (size_t)(n0 + w * 8 + srow) * KC + sgx * 8;
    u16* const As_w = &As[(w * 8) * 64];
    u16* const Bs_w = &Bs[(w * 8) * 64];

#pragma unroll 4
    for (int k0 = 0; k0 < KC; k0 += 64) {
        __syncthreads();
#pragma unroll
        for (int j = 0; j < 4; j++)
            gload_lds16(Ag + (size_t)(j * 32) * KC + k0, As_w + j * 32 * 64);
#pragma unroll
        for (int j = 0; j < 2; j++)
            gload_lds16(Bg + (size_t)(j * 32) * KC + k0, Bs_w + j * 32 * 64);
        __syncthreads();
#pragma unroll
        for (int ks4 = 0; ks4 < 2; ks4++) {
            bf16x8 af[2], bfr[4];
#pragma unroll
            for (int i = 0; i < 2; i++)
                af[i] = ldfrag(&As[(wm + i * 16 + ml) * 64 +
                                   (((ks4 * 4 + quad) ^ (ml & 7)) * 8)]);
#pragma unroll
            for (int i = 0; i < 4; i++)
                bfr[i] = ldfrag(&Bs[(i * 16 + ml) * 64 +
                                    (((ks4 * 4 + quad) ^ (ml & 7)) * 8)]);
#pragma unroll
            for (int mt = 0; mt < 2; mt++)
#pragma unroll
                for (int nt = 0; nt < 4; nt++)
                    acc[mt][nt] = __builtin_amdgcn_mfma_f32_16x16x32_bf16(
                        af[mt], bfr[nt], acc[mt][nt], 0, 0, 0);
        }
    }
#pragma unroll
    for (int mt = 0; mt < 2; mt++)
#pragma unroll
        for (int nt = 0; nt < 4; nt++)
#pragma unroll
            for (int rg = 0; rg < 4; rg++) {
                int m = m0 + wm + mt * 16 + quad * 4 + rg;
                int n = n0 + nt * 16 + ml;
                C[(size_t)m * Nst + n] = acc[mt][nt][rg] + Res[(size_t)m * Nst + n];
            }
}

// ---------------- depthwise causal conv(4) + bias + SiLU, 8-wide, + fused dt softplus ----------------
#define NGRAN (CONVDIM / 8)   // 288 granules of 8 channels per row
__global__ __launch_bounds__(256) void conv_silu_kernel(
    const u16* __restrict__ zx, const float* __restrict__ cw,
    const float* __restrict__ cb, const float* __restrict__ dt_bias,
    u16* __restrict__ out, float* __restrict__ dts)
{
    int idx = blockIdx.x * 256 + threadIdx.x;   // over NROWS*NGRAN
    if (idx < B_SZ * NHEADS * T_SZ) {           // fused softplus(dt)
        int t = idx & (T_SZ - 1);
        int bh = idx >> 11;
        int h = bh & 31, b = bh >> 5;
        float v = bf2f(zx[(size_t)(b * T_SZ + t) * DINPROJ + (DINNER + CONVDIM) + h]) + dt_bias[h];
        float sp = (v > 20.f) ? v : log1pf(expf(v));
        dts[((size_t)bh << 11) + t] = sp;
    }
    int gr = idx % NGRAN;
    int bt = idx / NGRAN;
    int t = bt & (T_SZ - 1);
    int c0 = gr * 8;
    float acc[8];
#pragma unroll
    for (int u = 0; u < 8; u++) acc[u] = cb[c0 + u];
    const u16* base = zx + (size_t)bt * DINPROJ + DINNER + c0;
#pragma unroll
    for (int k = 0; k < 4; k++) {
        int tt = t - 3 + k;
        if (tt >= 0) {
            u16x8 xv = *(const u16x8*)(base + (ptrdiff_t)(k - 3) * DINPROJ);
#pragma unroll
            for (int u = 0; u < 8; u++)
                acc[u] += bf2f(xv[u]) * cw[(c0 + u) * 4 + k];
        }
    }
    u16 res[8];
#pragma unroll
    for (int u = 0; u < 8; u++) {
        float s = acc[u] / (1.f + expf(-acc[u]));
        res[u] = f2bf(s);
    }
    *(u16x8*)&out[(size_t)bt * CONVDIM + c0] = *(u16x8*)res;
}

// ---------------- K1: per-chunk cumsum + chunk-local state S = Xw^T @ B ----------------
__global__ __launch_bounds__(256) void chunk_state_kernel(
    const u16* __restrict__ xbc, const float* __restrict__ dts_g,
    const float* __restrict__ A_log, float* __restrict__ cs_g, u16* __restrict__ S_bf)
{
    const int g = blockIdx.x;
    const int b = g >> 9, rem = g & 511, c = rem >> 5, h = rem & 31;
    const int tid = threadIdx.x;
    __shared__ float tmp[128], dt_l[128], d2e[128];
    __shared__ u16 Xw[64][136];
    __shared__ u16 BsT[128][136];
    const float A = -__expf(A_log[h]);
    if (tid < 128) {
        float d = dts_g[(((size_t)(b * 32 + h)) << 11) + (c << 7) + tid];
        dt_l[tid] = d; tmp[tid] = d * A;
    }
    __syncthreads();
    for (int off = 1; off < 128; off <<= 1) {
        float add = 0.f;
        if (tid < 128 && tid >= off) add = tmp[tid - off];
        __syncthreads();
        if (tid < 128) tmp[tid] += add;
        __syncthreads();
    }
    if (tid < 128) {
        float cs = tmp[tid];
        cs_g[(((size_t)(b * 32 + h)) << 11) + (c << 7) + tid] = cs;
        d2e[tid] = __expf(tmp[127] - cs) * dt_l[tid];
    }
    __syncthreads();
    const size_t rowbase = ((size_t)(b * T_SZ + c * L_CH)) * CONVDIM;
#pragma unroll
    for (int r = 0; r < 4; r++) {
        int v = tid + r * 256;
        int t = v >> 3, p0 = (v & 7) << 3;
        u16x8 xv = *(const u16x8*)&xbc[rowbase + (size_t)t * CONVDIM + h * 64 + p0];
        float s = d2e[t];
#pragma unroll
        for (int u = 0; u < 8; u++) Xw[p0 + u][t] = f2bf(bf2f(xv[u]) * s);
    }
#pragma unroll
    for (int r = 0; r < 8; r++) {
        int v = tid + r * 256;
        int t = v >> 4, n0 = (v & 15) << 3;
        u16x8 bv = *(const u16x8*)&xbc[rowbase + (size_t)t * CONVDIM + DINNER + n0];
#pragma unroll
        for (int u = 0; u < 8; u++) BsT[n0 + u][t] = bv[u];
    }
    __syncthreads();
    const int lane = tid & 63, wv = tid >> 6, ml = lane & 15, quad = lane >> 4;
    f32x4 acc[8] = {};
    for (int k0 = 0; k0 < 128; k0 += 32) {
        bf16x8 af = ldfrag(&Xw[wv * 16 + ml][k0 + quad * 8]);
#pragma unroll
        for (int nt = 0; nt < 8; nt++) {
            bf16x8 bf = ldfrag(&BsT[nt * 16 + ml][k0 + quad * 8]);
            acc[nt] = __builtin_amdgcn_mfma_f32_16x16x32_bf16(af, bf, acc[nt], 0, 0, 0);
        }
    }
    const size_t base = (size_t)g * 8192;
#pragma unroll
    for (int nt = 0; nt < 8; nt++) {
#pragma unroll
        for (int rg = 0; rg < 4; rg++) {
            int p = wv * 16 + quad * 4 + rg, n = nt * 16 + ml;
            S_bf[base + p * 128 + n] = f2bf(acc[nt][rg]);
        }
    }
}

// ---------------- K2: inter-chunk recurrence, in-place ----------------
__global__ __launch_bounds__(256) void state_pass_kernel(
    const float* __restrict__ cs_g, u16* __restrict__ S_bf)
{
    const int bh = blockIdx.x, b = bh >> 5, h = bh & 31;
    const int tid = threadIdx.x;
    float H[32];
#pragma unroll
    for (int i = 0; i < 32; i++) H[i] = 0.f;
    for (int c = 0; c < NCH; c++) {
        float decay = __expf(cs_g[(((size_t)(b * 32 + h)) << 11) + (c << 7) + 127]);
        size_t slot = ((size_t)((b * NCH + c) * 32 + h)) * 8192 + tid * 32;
        u16 tv[32];
#pragma unroll
        for (int q = 0; q < 4; q++)
            *(u16x8*)&tv[q * 8] = *(const u16x8*)&S_bf[slot + q * 8];
        u16 hw[32];
#pragma unroll
        for (int i = 0; i < 32; i++) hw[i] = f2bf(H[i]);
#pragma unroll
        for (int q = 0; q < 4; q++)
            *(u16x8*)&S_bf[slot + q * 8] = *(const u16x8*)&hw[q * 8];
#pragma unroll
        for (int i = 0; i < 32; i++) H[i] = H[i] * decay + bf2f(tv[i]);
    }
}

// ---------------- K3: chunk output ----------------
__global__ __launch_bounds__(256) void chunk_out_kernel(
    const u16* __restrict__ xbc, const float* __restrict__ dts_g,
    const float* __restrict__ cs_g, const u16* __restrict__ H_bf,
    const float* __restrict__ Dv, u16* __restrict__ yraw)
{
    const int g = blockIdx.x;
    const int b = g >> 9, rem = g & 511, c = rem >> 5, h = rem & 31;
    const int tid = threadIdx.x;
    __shared__ u16 Cs[128][136];
    __shared__ u16 Bs[128][136];
    __shared__ u16 Xs[64][136];
    __shared__ u16 Hs[64][136];
    __shared__ u16 Gs[128][40];
    __shared__ float cs_l[128], P_l[128], dt_l[128];
    const size_t rowbase = ((size_t)(b * T_SZ + c * L_CH)) * CONVDIM;
    if (tid < 128) {
        float cs = cs_g[(((size_t)(b * 32 + h)) << 11) + (c << 7) + tid];
        cs_l[tid] = cs; P_l[tid] = __expf(cs);
        dt_l[tid] = dts_g[(((size_t)(b * 32 + h)) << 11) + (c << 7) + tid];
    }
#pragma unroll
    for (int r = 0; r < 8; r++) {
        int v = tid + r * 256; int t = v >> 4, n0 = (v & 15) << 3;
        *(u16x8*)&Cs[t][n0] = *(const u16x8*)&xbc[rowbase + (size_t)t * CONVDIM + DINNER + 128 + n0];
        *(u16x8*)&Bs[t][n0] = *(const u16x8*)&xbc[rowbase + (size_t)t * CONVDIM + DINNER + n0];
    }
#pragma unroll
    for (int r = 0; r < 4; r++) {
        int v = tid + r * 256; int t = v >> 3, p0 = (v & 7) << 3;
        u16x8 xv = *(const u16x8*)&xbc[rowbase + (size_t)t * CONVDIM + h * 64 + p0];
#pragma unroll
        for (int u = 0; u < 8; u++) Xs[p0 + u][t] = xv[u];
    }
    {
        const size_t hbase = (size_t)g * 8192;
#pragma unroll
        for (int r = 0; r < 4; r++) {
            int v = tid + r * 256; int p = v >> 4, n0 = (v & 15) << 3;
            *(u16x8*)&Hs[p][n0] = *(const u16x8*)&H_bf[hbase + p * 128 + n0];
        }
    }
    __syncthreads();
    const int lane = tid & 63, wv = tid >> 6, ml = lane & 15, quad = lane >> 4;
    const int trow = wv * 32;
    f32x4 accY[2][4] = {};
    for (int k0 = 0; k0 < 128; k0 += 32) {
        bf16x8 af0 = ldfrag(&Cs[trow + ml][k0 + quad * 8]);
        bf16x8 af1 = ldfrag(&Cs[trow + 16 + ml][k0 + quad * 8]);
#pragma unroll
        for (int pt = 0; pt < 4; pt++) {
            bf16x8 bf = ldfrag(&Hs[pt * 16 + ml][k0 + quad * 8]);
            accY[0][pt] = __builtin_amdgcn_mfma_f32_16x16x32_bf16(af0, bf, accY[0][pt], 0, 0, 0);
            accY[1][pt] = __builtin_amdgcn_mfma_f32_16x16x32_bf16(af1, bf, accY[1][pt], 0, 0, 0);
        }
    }
#pragma unroll
    for (int mt = 0; mt < 2; mt++) {
#pragma unroll
        for (int rg = 0; rg < 4; rg++) {
            float pp = P_l[trow + mt * 16 + quad * 4 + rg];
#pragma unroll
            for (int pt = 0; pt < 4; pt++) accY[mt][pt][rg] *= pp;
        }
    }
    for (int js = 0; js < 4; js++) {
        const int j0 = js * 32;
        f32x4 Ga[2][2] = {};
        for (int k0 = 0; k0 < 128; k0 += 32) {
            bf16x8 af0 = ldfrag(&Cs[trow + ml][k0 + quad * 8]);
            bf16x8 af1 = ldfrag(&Cs[trow + 16 + ml][k0 + quad * 8]);
            bf16x8 bf0 = ldfrag(&Bs[j0 + ml][k0 + quad * 8]);
            bf16x8 bf1 = ldfrag(&Bs[j0 + 16 + ml][k0 + quad * 8]);
            Ga[0][0] = __builtin_amdgcn_mfma_f32_16x16x32_bf16(af0, bf0, Ga[0][0], 0, 0, 0);
            Ga[0][1] = __builtin_amdgcn_mfma_f32_16x16x32_bf16(af0, bf1, Ga[0][1], 0, 0, 0);
            Ga[1][0] = __builtin_amdgcn_mfma_f32_16x16x32_bf16(af1, bf0, Ga[1][0], 0, 0, 0);
            Ga[1][1] = __builtin_amdgcn_mfma_f32_16x16x32_bf16(af1, bf1, Ga[1][1], 0, 0, 0);
        }
#pragma unroll
        for (int mt = 0; mt < 2; mt++) {
#pragma unroll
            for (int jt = 0; jt < 2; jt++) {
#pragma unroll
                for (int rg = 0; rg < 4; rg++) {
                    int t = trow + mt * 16 + quad * 4 + rg;
                    int j = j0 + jt * 16 + ml;
                    float val = 0.f;
                    if (t >= j) val = Ga[mt][jt][rg] * __expf(cs_l[t] - cs_l[j]) * dt_l[j];
                    Gs[t][jt * 16 + ml] = f2bf(val);
                }
            }
        }
#pragma unroll
        for (int mt = 0; mt < 2; mt++) {
            bf16x8 af = ldfrag(&Gs[trow + mt * 16 + ml][quad * 8]);
#pragma unroll
            for (int pt = 0; pt < 4; pt++) {
                bf16x8 bf = ldfrag(&Xs[pt * 16 + ml][j0 + quad * 8]);
                accY[mt][pt] = __builtin_amdgcn_mfma_f32_16x16x32_bf16(af, bf, accY[mt][pt], 0, 0, 0);
            }
        }
    }
    const float Dh = Dv[h];
    const size_t ybase = ((size_t)(b * T_SZ + c * L_CH)) * DINNER;
#pragma unroll
    for (int mt = 0; mt < 2; mt++) {
#pragma unroll
        for (int pt = 0; pt < 4; pt++) {
#pragma unroll
            for (int rg = 0; rg < 4; rg++) {
                int t = trow + mt * 16 + quad * 4 + rg;
                int p = pt * 16 + ml;
                float v = accY[mt][pt][rg] + Dh * bf2f(Xs[p][t]);
                yraw[ybase + (size_t)t * DINNER + h * 64 + p] = f2bf(v);
            }
        }
    }
}

// ---------------- y = rmsnorm(yraw * silu(z)) * gnorm_w (D=2048) ----------------
__global__ __launch_bounds__(256) void postnorm_kernel(
    const u16* __restrict__ yraw, const u16* __restrict__ zx,
    const float* __restrict__ gw, u16* __restrict__ out)
{
    const int row = blockIdx.x;
    const u16* yr = yraw + (size_t)row * DINNER;
    const u16* zr = zx + (size_t)row * DINPROJ;
    float vals[8]; float ss = 0.f;
#pragma unroll
    for (int i = 0; i < 8; i++) {
        int c = threadIdx.x + i * 256;
        float y = bf2f(yr[c]);
        float z = bf2f(zr[c]);
        float s = z / (1.f + expf(-z));
        float t = y * s; vals[i] = t; ss += t * t;
    }
#pragma unroll
    for (int o = 32; o; o >>= 1) ss += __shfl_xor(ss, o);
    __shared__ float red[4];
    if ((threadIdx.x & 63) == 0) red[threadIdx.x >> 6] = ss;
    __syncthreads();
    ss = red[0] + red[1] + red[2] + red[3];
    float sc = rsqrtf(ss / (float)DINNER + 1e-5f);
#pragma unroll
    for (int i = 0; i < 8; i++) {
        int c = threadIdx.x + i * 256;
        out[(size_t)row * DINNER + c] = f2bf(vals[i] * sc * gw[c]);
    }
}

extern "C" void kernel_launch(void* const* d_in, const int* in_sizes, int n_in,
                              void* d_out, int out_size, void* d_ws, size_t ws_size,
                              hipStream_t stream) {
    const float* x       = (const float*)d_in[0];
    const float* W_in    = (const float*)d_in[1];
    const float* conv_w  = (const float*)d_in[2];
    const float* conv_b  = (const float*)d_in[3];
    const float* dt_bias = (const float*)d_in[4];
    const float* A_log   = (const float*)d_in[5];
    const float* Dv      = (const float*)d_in[6];
    const float* norm_w  = (const float*)d_in[7];
    const float* gnorm_w = (const float*)d_in[8];
    const float* W_out   = (const float*)d_in[9];
    float* out = (float*)d_out;

    char* ws = (char*)d_ws;
    u16*   xn    = (u16*)(ws);
    u16*   W_inT = (u16*)(ws + 8388608);        // [4480][1024] bf16
    u16*   S_bf  = (u16*)(ws);                  // aliases xn/W_inT (dead by K1)
    float* cs_g  = (float*)(ws + 16777216);
    u16*   W_outT= (u16*)(ws);                  // [1024][2048] bf16, after S_bf dead
    u16*   zx    = (u16*)(ws + 17563648);       // 35,913,728 B
    u16*   xbc   = (u16*)(ws + 53477376);       // 18,874,368 B
    float* dts   = (float*)(ws + 72351744);     //    524,288 B
    u16*   yraw  = (u16*)(ws + 72876032);       // 16,777,216 B (end 89,653,248)
    u16*   ynorm = yraw;                        // postnorm in-place safe

    trans_kernel<<<dim3(DINPROJ_P / 64, DMODEL / 64), 256, 0, stream>>>(
        W_in, W_inT, DMODEL, DINPROJ);
    rmsnorm_in_kernel<<<NROWS, 256, 0, stream>>>(x, norm_w, xn);
    gemm128_kernel<0, DMODEL><<<(DINPROJ_P / 128) * (NROWS / 128), 256, 0, stream>>>(
        xn, W_inT, zx, nullptr, DINPROJ, DINPROJ_P / 128);
    conv_silu_kernel<<<(NROWS * NGRAN) / 256, 256, 0, stream>>>(
        zx, conv_w, conv_b, dt_bias, xbc, dts);
    chunk_state_kernel<<<B_SZ * NCH * NHEADS, 256, 0, stream>>>(xbc, dts, A_log, cs_g, S_bf);
    state_pass_kernel<<<B_SZ * NHEADS, 256, 0, stream>>>(cs_g, S_bf);
    chunk_out_kernel<<<B_SZ * NCH * NHEADS, 256, 0, stream>>>(xbc, dts, cs_g, S_bf, Dv, yraw);
    trans_kernel<<<dim3(DMODEL / 64, DINNER / 64), 256, 0, stream>>>(
        W_out, W_outT, DINNER, DMODEL);
    postnorm_kernel<<<NROWS, 256, 0, stream>>>(yraw, zx, gnorm_w, ynorm);
    gemm128x64_kernel<DINNER><<<(DMODEL / 64) * (NROWS / 128), 256, 0, stream>>>(
        ynorm, W_outT, out, x, DMODEL, DMODEL / 64);
}

// Round 7
// 308.699 us; speedup vs baseline: 1.1352x; 1.1352x over previous
//
#include <hip/hip_runtime.h>
#include <hip/hip_bf16.h>

typedef unsigned short u16;
typedef unsigned int u32;
typedef u16 u16x8 __attribute__((ext_vector_type(8)));
typedef __bf16 bf16x8 __attribute__((ext_vector_type(8)));
typedef float f32x4 __attribute__((ext_vector_type(4)));

#define B_SZ 2
#define T_SZ 2048
#define DMODEL 1024
#define DINNER 2048
#define DSTATE 128
#define NHEADS 32
#define HEADDIM 64
#define CONVDIM 2304
#define DINPROJ 4384
#define DINPROJ_P 4480        // padded to 35*128 for GEMM1 tiles
#define NROWS (B_SZ * T_SZ)   // 4096
#define L_CH 128
#define NCH 16                // chunks per batch (T/L)

__device__ __forceinline__ float bf2f(u16 u) {
    union { float f; u32 i; } v; v.i = ((u32)u) << 16; return v.f;
}
__device__ __forceinline__ u16 f2bf(float f) {
    union { float f; u32 i; } v; v.f = f;
    u32 r = v.i + 0x7FFFu + ((v.i >> 16) & 1u);
    return (u16)(r >> 16);
}
__device__ __forceinline__ bf16x8 ldfrag(const u16* p) {
    return __builtin_bit_cast(bf16x8, *(const u16x8*)p);
}
__device__ __forceinline__ void gload_lds16(const u16* g, u16* l) {
    __builtin_amdgcn_global_load_lds(
        (const __attribute__((address_space(1))) unsigned int*)g,
        (__attribute__((address_space(3))) unsigned int*)l, 16, 0, 0);
}

// ---------------- transpose + f32->bf16: out[n][k] = in[k][n] ----------------
__global__ __launch_bounds__(256) void trans_kernel(
    const float* __restrict__ in, u16* __restrict__ out, int K, int N)
{
    __shared__ u16 tile[64][66];
    const int n0 = blockIdx.x * 64, k0 = blockIdx.y * 64;
    const int tid = threadIdx.x;
#pragma unroll
    for (int r = 0; r < 16; r++) {
        int idx = r * 256 + tid;
        int k = idx >> 6, n = idx & 63;
        float v = (n0 + n < N) ? in[(size_t)(k0 + k) * N + n0 + n] : 0.f;
        tile[n][k] = f2bf(v);
    }
    __syncthreads();
#pragma unroll
    for (int r = 0; r < 16; r++) {
        int idx = r * 256 + tid;
        int n = idx >> 6, k = idx & 63;
        out[(size_t)(n0 + n) * K + k0 + k] = tile[n][k];
    }
}

// ---------------- conv weight repack: cwT[k][c] = bf16(cw[c][k]) ----------------
__global__ __launch_bounds__(256) void cwprep_kernel(
    const float* __restrict__ cw, u16* __restrict__ cwT)
{
    int idx = blockIdx.x * 256 + threadIdx.x;   // over 4*CONVDIM
    if (idx < 4 * CONVDIM) {
        int k = idx / CONVDIM, c = idx - k * CONVDIM;
        cwT[idx] = f2bf(cw[c * 4 + k]);
    }
}

// ---------------- RMSNorm on input (D=1024), f32 in -> bf16 out ----------------
__global__ __launch_bounds__(256) void rmsnorm_in_kernel(
    const float* __restrict__ x, const float* __restrict__ w, u16* __restrict__ out)
{
    const int row = blockIdx.x;
    const float* xr = x + (size_t)row * DMODEL;
    float vals[4]; float ss = 0.f;
#pragma unroll
    for (int i = 0; i < 4; i++) {
        int c = threadIdx.x + i * 256;
        float v = xr[c]; vals[i] = v; ss += v * v;
    }
#pragma unroll
    for (int o = 32; o; o >>= 1) ss += __shfl_xor(ss, o);
    __shared__ float red[4];
    if ((threadIdx.x & 63) == 0) red[threadIdx.x >> 6] = ss;
    __syncthreads();
    ss = red[0] + red[1] + red[2] + red[3];
    float sc = rsqrtf(ss / (float)DMODEL + 1e-5f);
#pragma unroll
    for (int i = 0; i < 4; i++) {
        int c = threadIdx.x + i * 256;
        out[(size_t)row * DMODEL + c] = f2bf(vals[i] * sc * w[c]);
    }
}

// ---------------- 128x128 bf16 MFMA GEMM, BK=64, XOR-swizzled, compile-time K ----------------
template<int MODE, int KC>
__global__ __launch_bounds__(256) void gemm128_kernel(
    const u16* __restrict__ A, const u16* __restrict__ BT, void* __restrict__ Cv,
    const float* __restrict__ Res, int Nst, int nbx)
{
    __shared__ u16 As[128 * 64];
    __shared__ u16 Bs[128 * 64];
    const int tid = threadIdx.x;
    const int l = tid & 63, w = tid >> 6;
    const int per = nbx * 8;
    const int grp = blockIdx.x / per, r = blockIdx.x % per;
    const int m0 = (grp * 8 + (r & 7)) * 128;
    const int n0 = (r >> 3) * 128;
    const int ml = l & 15, quad = l >> 4;
    const int wm = (w & 1) * 64, wn = (w >> 1) * 64;
    f32x4 acc[4][4] = {};
    const int srow = l >> 3;
    const int sgx = (l & 7) ^ srow;
    const u16* Ag = A + (size_t)(m0 + w * 8 + srow) * KC + sgx * 8;
    const u16* Bg = BT + (size_t)(n0 + w * 8 + srow) * KC + sgx * 8;
    u16* const As_w = &As[(w * 8) * 64];
    u16* const Bs_w = &Bs[(w * 8) * 64];

#pragma unroll 4
    for (int k0 = 0; k0 < KC; k0 += 64) {
        __syncthreads();
#pragma unroll
        for (int j = 0; j < 4; j++) {
            gload_lds16(Ag + (size_t)(j * 32) * KC + k0, As_w + j * 32 * 64);
            gload_lds16(Bg + (size_t)(j * 32) * KC + k0, Bs_w + j * 32 * 64);
        }
        __syncthreads();
#pragma unroll
        for (int ks4 = 0; ks4 < 2; ks4++) {
            bf16x8 af[4], bfr[4];
#pragma unroll
            for (int i = 0; i < 4; i++)
                af[i] = ldfrag(&As[(wm + i * 16 + ml) * 64 +
                                   (((ks4 * 4 + quad) ^ (ml & 7)) * 8)]);
#pragma unroll
            for (int i = 0; i < 4; i++)
                bfr[i] = ldfrag(&Bs[(wn + i * 16 + ml) * 64 +
                                    (((ks4 * 4 + quad) ^ (ml & 7)) * 8)]);
#pragma unroll
            for (int mt = 0; mt < 4; mt++)
#pragma unroll
                for (int nt = 0; nt < 4; nt++)
                    acc[mt][nt] = __builtin_amdgcn_mfma_f32_16x16x32_bf16(
                        af[mt], bfr[nt], acc[mt][nt], 0, 0, 0);
        }
    }
#pragma unroll
    for (int mt = 0; mt < 4; mt++)
#pragma unroll
        for (int nt = 0; nt < 4; nt++)
#pragma unroll
            for (int rg = 0; rg < 4; rg++) {
                int m = m0 + wm + mt * 16 + quad * 4 + rg;
                int n = n0 + wn + nt * 16 + ml;
                if (n < Nst) {
                    if (MODE == 0)
                        ((u16*)Cv)[(size_t)m * Nst + n] = f2bf(acc[mt][nt][rg]);
                    else
                        ((float*)Cv)[(size_t)m * Nst + n] =
                            acc[mt][nt][rg] + Res[(size_t)m * Nst + n];
                }
            }
}

// ---------------- 128(M)x64(N) bf16 MFMA GEMM, BK=64, swizzled, compile-time K ----------------
template<int KC>
__global__ __launch_bounds__(256) void gemm128x64_kernel(
    const u16* __restrict__ A, const u16* __restrict__ BT, float* __restrict__ C,
    const float* __restrict__ Res, int Nst, int nbx)
{
    __shared__ u16 As[128 * 64];
    __shared__ u16 Bs[64 * 64];
    const int tid = threadIdx.x;
    const int l = tid & 63, w = tid >> 6;
    const int per = nbx * 8;
    const int grp = blockIdx.x / per, r = blockIdx.x % per;
    const int m0 = (grp * 8 + (r & 7)) * 128;
    const int n0 = (r >> 3) * 64;
    const int ml = l & 15, quad = l >> 4;
    const int wm = w * 32;
    f32x4 acc[2][4] = {};
    const int srow = l >> 3;
    const int sgx = (l & 7) ^ srow;
    const u16* Ag = A + (size_t)(m0 + w * 8 + srow) * KC + sgx * 8;
    const u16* Bg = BT + (size_t)(n0 + w * 8 + srow) * KC + sgx * 8;
    u16* const As_w = &As[(w * 8) * 64];
    u16* const Bs_w = &Bs[(w * 8) * 64];

#pragma unroll 4
    for (int k0 = 0; k0 < KC; k0 += 64) {
        __syncthreads();
#pragma unroll
        for (int j = 0; j < 4; j++)
            gload_lds16(Ag + (size_t)(j * 32) * KC + k0, As_w + j * 32 * 64);
#pragma unroll
        for (int j = 0; j < 2; j++)
            gload_lds16(Bg + (size_t)(j * 32) * KC + k0, Bs_w + j * 32 * 64);
        __syncthreads();
#pragma unroll
        for (int ks4 = 0; ks4 < 2; ks4++) {
            bf16x8 af[2], bfr[4];
#pragma unroll
            for (int i = 0; i < 2; i++)
                af[i] = ldfrag(&As[(wm + i * 16 + ml) * 64 +
                                   (((ks4 * 4 + quad) ^ (ml & 7)) * 8)]);
#pragma unroll
            for (int i = 0; i < 4; i++)
                bfr[i] = ldfrag(&Bs[(i * 16 + ml) * 64 +
                                    (((ks4 * 4 + quad) ^ (ml & 7)) * 8)]);
#pragma unroll
            for (int mt = 0; mt < 2; mt++)
#pragma unroll
                for (int nt = 0; nt < 4; nt++)
                    acc[mt][nt] = __builtin_amdgcn_mfma_f32_16x16x32_bf16(
                        af[mt], bfr[nt], acc[mt][nt], 0, 0, 0);
        }
    }
#pragma unroll
    for (int mt = 0; mt < 2; mt++)
#pragma unroll
        for (int nt = 0; nt < 4; nt++)
#pragma unroll
            for (int rg = 0; rg < 4; rg++) {
                int m = m0 + wm + mt * 16 + quad * 4 + rg;
                int n = n0 + nt * 16 + ml;
                C[(size_t)m * Nst + n] = acc[mt][nt][rg] + Res[(size_t)m * Nst + n];
            }
}

// ---------------- depthwise causal conv(4) + bias + SiLU, 8-wide, coalesced weights ----------------
#define NGRAN (CONVDIM / 8)   // 288 granules of 8 channels per row
__global__ __launch_bounds__(256) void conv_silu_kernel(
    const u16* __restrict__ zx, const u16* __restrict__ cwT,
    const float* __restrict__ cb, const float* __restrict__ dt_bias,
    u16* __restrict__ out, float* __restrict__ dts)
{
    int idx = blockIdx.x * 256 + threadIdx.x;   // over NROWS*NGRAN
    if (idx < B_SZ * NHEADS * T_SZ) {           // fused softplus(dt)
        int t = idx & (T_SZ - 1);
        int bh = idx >> 11;
        int h = bh & 31, b = bh >> 5;
        float v = bf2f(zx[(size_t)(b * T_SZ + t) * DINPROJ + (DINNER + CONVDIM) + h]) + dt_bias[h];
        float sp = (v > 20.f) ? v : log1pf(expf(v));
        dts[((size_t)bh << 11) + t] = sp;
    }
    int gr = idx % NGRAN;
    int bt = idx / NGRAN;
    int t = bt & (T_SZ - 1);
    int c0 = gr * 8;
    float acc[8];
#pragma unroll
    for (int u = 0; u < 8; u++) acc[u] = cb[c0 + u];
    const u16* base = zx + (size_t)bt * DINPROJ + DINNER + c0;
#pragma unroll
    for (int k = 0; k < 4; k++) {
        int tt = t - 3 + k;
        if (tt >= 0) {
            u16x8 xv = *(const u16x8*)(base + (ptrdiff_t)(k - 3) * DINPROJ);
            u16x8 wv = *(const u16x8*)&cwT[k * CONVDIM + c0];
#pragma unroll
            for (int u = 0; u < 8; u++)
                acc[u] += bf2f(xv[u]) * bf2f(wv[u]);
        }
    }
    u16 res[8];
#pragma unroll
    for (int u = 0; u < 8; u++) {
        float s = acc[u] / (1.f + expf(-acc[u]));
        res[u] = f2bf(s);
    }
    *(u16x8*)&out[(size_t)bt * CONVDIM + c0] = *(u16x8*)res;
}

// ---------------- K1: per-chunk cumsum + chunk-local state S = Xw^T @ B ----------------
__global__ __launch_bounds__(256) void chunk_state_kernel(
    const u16* __restrict__ xbc, const float* __restrict__ dts_g,
    const float* __restrict__ A_log, float* __restrict__ cs_g, u16* __restrict__ S_bf)
{
    const int g = blockIdx.x;
    const int b = g >> 9, rem = g & 511, c = rem >> 5, h = rem & 31;
    const int tid = threadIdx.x;
    __shared__ float tmp[128], dt_l[128], d2e[128];
    __shared__ u16 Xw[64][136];
    __shared__ u16 BsT[128][136];
    const float A = -__expf(A_log[h]);
    if (tid < 128) {
        float d = dts_g[(((size_t)(b * 32 + h)) << 11) + (c << 7) + tid];
        dt_l[tid] = d; tmp[tid] = d * A;
    }
    __syncthreads();
    for (int off = 1; off < 128; off <<= 1) {
        float add = 0.f;
        if (tid < 128 && tid >= off) add = tmp[tid - off];
        __syncthreads();
        if (tid < 128) tmp[tid] += add;
        __syncthreads();
    }
    if (tid < 128) {
        float cs = tmp[tid];
        cs_g[(((size_t)(b * 32 + h)) << 11) + (c << 7) + tid] = cs;
        d2e[tid] = __expf(tmp[127] - cs) * dt_l[tid];
    }
    __syncthreads();
    const size_t rowbase = ((size_t)(b * T_SZ + c * L_CH)) * CONVDIM;
#pragma unroll
    for (int r = 0; r < 4; r++) {
        int v = tid + r * 256;
        int t = v >> 3, p0 = (v & 7) << 3;
        u16x8 xv = *(const u16x8*)&xbc[rowbase + (size_t)t * CONVDIM + h * 64 + p0];
        float s = d2e[t];
#pragma unroll
        for (int u = 0; u < 8; u++) Xw[p0 + u][t] = f2bf(bf2f(xv[u]) * s);
    }
#pragma unroll
    for (int r = 0; r < 8; r++) {
        int v = tid + r * 256;
        int t = v >> 4, n0 = (v & 15) << 3;
        u16x8 bv = *(const u16x8*)&xbc[rowbase + (size_t)t * CONVDIM + DINNER + n0];
#pragma unroll
        for (int u = 0; u < 8; u++) BsT[n0 + u][t] = bv[u];
    }
    __syncthreads();
    const int lane = tid & 63, wv = tid >> 6, ml = lane & 15, quad = lane >> 4;
    f32x4 acc[8] = {};
    for (int k0 = 0; k0 < 128; k0 += 32) {
        bf16x8 af = ldfrag(&Xw[wv * 16 + ml][k0 + quad * 8]);
#pragma unroll
        for (int nt = 0; nt < 8; nt++) {
            bf16x8 bf = ldfrag(&BsT[nt * 16 + ml][k0 + quad * 8]);
            acc[nt] = __builtin_amdgcn_mfma_f32_16x16x32_bf16(af, bf, acc[nt], 0, 0, 0);
        }
    }
    const size_t base = (size_t)g * 8192;
#pragma unroll
    for (int nt = 0; nt < 8; nt++) {
#pragma unroll
        for (int rg = 0; rg < 4; rg++) {
            int p = wv * 16 + quad * 4 + rg, n = nt * 16 + ml;
            S_bf[base + p * 128 + n] = f2bf(acc[nt][rg]);
        }
    }
}

// ---------------- K2: inter-chunk recurrence, in-place ----------------
__global__ __launch_bounds__(256) void state_pass_kernel(
    const float* __restrict__ cs_g, u16* __restrict__ S_bf)
{
    const int bh = blockIdx.x, b = bh >> 5, h = bh & 31;
    const int tid = threadIdx.x;
    float H[32];
#pragma unroll
    for (int i = 0; i < 32; i++) H[i] = 0.f;
    for (int c = 0; c < NCH; c++) {
        float decay = __expf(cs_g[(((size_t)(b * 32 + h)) << 11) + (c << 7) + 127]);
        size_t slot = ((size_t)((b * NCH + c) * 32 + h)) * 8192 + tid * 32;
        u16 tv[32];
#pragma unroll
        for (int q = 0; q < 4; q++)
            *(u16x8*)&tv[q * 8] = *(const u16x8*)&S_bf[slot + q * 8];
        u16 hw[32];
#pragma unroll
        for (int i = 0; i < 32; i++) hw[i] = f2bf(H[i]);
#pragma unroll
        for (int q = 0; q < 4; q++)
            *(u16x8*)&S_bf[slot + q * 8] = *(const u16x8*)&hw[q * 8];
#pragma unroll
        for (int i = 0; i < 32; i++) H[i] = H[i] * decay + bf2f(tv[i]);
    }
}

// ---------------- K3: chunk output ----------------
__global__ __launch_bounds__(256) void chunk_out_kernel(
    const u16* __restrict__ xbc, const float* __restrict__ dts_g,
    const float* __restrict__ cs_g, const u16* __restrict__ H_bf,
    const float* __restrict__ Dv, u16* __restrict__ yraw)
{
    const int g = blockIdx.x;
    const int b = g >> 9, rem = g & 511, c = rem >> 5, h = rem & 31;
    const int tid = threadIdx.x;
    __shared__ u16 Cs[128][136];
    __shared__ u16 Bs[128][136];
    __shared__ u16 Xs[64][136];
    __shared__ u16 Hs[64][136];
    __shared__ u16 Gs[128][40];
    __shared__ float cs_l[128], P_l[128], dt_l[128];
    const size_t rowbase = ((size_t)(b * T_SZ + c * L_CH)) * CONVDIM;
    if (tid < 128) {
        float cs = cs_g[(((size_t)(b * 32 + h)) << 11) + (c << 7) + tid];
        cs_l[tid] = cs; P_l[tid] = __expf(cs);
        dt_l[tid] = dts_g[(((size_t)(b * 32 + h)) << 11) + (c << 7) + tid];
    }
#pragma unroll
    for (int r = 0; r < 8; r++) {
        int v = tid + r * 256; int t = v >> 4, n0 = (v & 15) << 3;
        *(u16x8*)&Cs[t][n0] = *(const u16x8*)&xbc[rowbase + (size_t)t * CONVDIM + DINNER + 128 + n0];
        *(u16x8*)&Bs[t][n0] = *(const u16x8*)&xbc[rowbase + (size_t)t * CONVDIM + DINNER + n0];
    }
#pragma unroll
    for (int r = 0; r < 4; r++) {
        int v = tid + r * 256; int t = v >> 3, p0 = (v & 7) << 3;
        u16x8 xv = *(const u16x8*)&xbc[rowbase + (size_t)t * CONVDIM + h * 64 + p0];
#pragma unroll
        for (int u = 0; u < 8; u++) Xs[p0 + u][t] = xv[u];
    }
    {
        const size_t hbase = (size_t)g * 8192;
#pragma unroll
        for (int r = 0; r < 4; r++) {
            int v = tid + r * 256; int p = v >> 4, n0 = (v & 15) << 3;
            *(u16x8*)&Hs[p][n0] = *(const u16x8*)&H_bf[hbase + p * 128 + n0];
        }
    }
    __syncthreads();
    const int lane = tid & 63, wv = tid >> 6, ml = lane & 15, quad = lane >> 4;
    const int trow = wv * 32;
    f32x4 accY[2][4] = {};
    for (int k0 = 0; k0 < 128; k0 += 32) {
        bf16x8 af0 = ldfrag(&Cs[trow + ml][k0 + quad * 8]);
        bf16x8 af1 = ldfrag(&Cs[trow + 16 + ml][k0 + quad * 8]);
#pragma unroll
        for (int pt = 0; pt < 4; pt++) {
            bf16x8 bf = ldfrag(&Hs[pt * 16 + ml][k0 + quad * 8]);
            accY[0][pt] = __builtin_amdgcn_mfma_f32_16x16x32_bf16(af0, bf, accY[0][pt], 0, 0, 0);
            accY[1][pt] = __builtin_amdgcn_mfma_f32_16x16x32_bf16(af1, bf, accY[1][pt], 0, 0, 0);
        }
    }
#pragma unroll
    for (int mt = 0; mt < 2; mt++) {
#pragma unroll
        for (int rg = 0; rg < 4; rg++) {
            float pp = P_l[trow + mt * 16 + quad * 4 + rg];
#pragma unroll
            for (int pt = 0; pt < 4; pt++) accY[mt][pt][rg] *= pp;
        }
    }
    for (int js = 0; js < 4; js++) {
        const int j0 = js * 32;
        f32x4 Ga[2][2] = {};
        for (int k0 = 0; k0 < 128; k0 += 32) {
            bf16x8 af0 = ldfrag(&Cs[trow + ml][k0 + quad * 8]);
            bf16x8 af1 = ldfrag(&Cs[trow + 16 + ml][k0 + quad * 8]);
            bf16x8 bf0 = ldfrag(&Bs[j0 + ml][k0 + quad * 8]);
            bf16x8 bf1 = ldfrag(&Bs[j0 + 16 + ml][k0 + quad * 8]);
            Ga[0][0] = __builtin_amdgcn_mfma_f32_16x16x32_bf16(af0, bf0, Ga[0][0], 0, 0, 0);
            Ga[0][1] = __builtin_amdgcn_mfma_f32_16x16x32_bf16(af0, bf1, Ga[0][1], 0, 0, 0);
            Ga[1][0] = __builtin_amdgcn_mfma_f32_16x16x32_bf16(af1, bf0, Ga[1][0], 0, 0, 0);
            Ga[1][1] = __builtin_amdgcn_mfma_f32_16x16x32_bf16(af1, bf1, Ga[1][1], 0, 0, 0);
        }
#pragma unroll
        for (int mt = 0; mt < 2; mt++) {
#pragma unroll
            for (int jt = 0; jt < 2; jt++) {
#pragma unroll
                for (int rg = 0; rg < 4; rg++) {
                    int t = trow + mt * 16 + quad * 4 + rg;
                    int j = j0 + jt * 16 + ml;
                    float val = 0.f;
                    if (t >= j) val = Ga[mt][jt][rg] * __expf(cs_l[t] - cs_l[j]) * dt_l[j];
                    Gs[t][jt * 16 + ml] = f2bf(val);
                }
            }
        }
#pragma unroll
        for (int mt = 0; mt < 2; mt++) {
            bf16x8 af = ldfrag(&Gs[trow + mt * 16 + ml][quad * 8]);
#pragma unroll
            for (int pt = 0; pt < 4; pt++) {
                bf16x8 bf = ldfrag(&Xs[pt * 16 + ml][j0 + quad * 8]);
                accY[mt][pt] = __builtin_amdgcn_mfma_f32_16x16x32_bf16(af, bf, accY[mt][pt], 0, 0, 0);
            }
        }
    }
    const float Dh = Dv[h];
    const size_t ybase = ((size_t)(b * T_SZ + c * L_CH)) * DINNER;
#pragma unroll
    for (int mt = 0; mt < 2; mt++) {
#pragma unroll
        for (int pt = 0; pt < 4; pt++) {
#pragma unroll
            for (int rg = 0; rg < 4; rg++) {
                int t = trow + mt * 16 + quad * 4 + rg;
                int p = pt * 16 + ml;
                float v = accY[mt][pt][rg] + Dh * bf2f(Xs[p][t]);
                yraw[ybase + (size_t)t * DINNER + h * 64 + p] = f2bf(v);
            }
        }
    }
}

// ---------------- y = rmsnorm(yraw * silu(z)) * gnorm_w (D=2048) ----------------
__global__ __launch_bounds__(256) void postnorm_kernel(
    const u16* __restrict__ yraw, const u16* __restrict__ zx,
    const float* __restrict__ gw, u16* __restrict__ out)
{
    const int row = blockIdx.x;
    const u16* yr = yraw + (size_t)row * DINNER;
    const u16* zr = zx + (size_t)row * DINPROJ;
    float vals[8]; float ss = 0.f;
#pragma unroll
    for (int i = 0; i < 8; i++) {
        int c = threadIdx.x + i * 256;
        float y = bf2f(yr[c]);
        float z = bf2f(zr[c]);
        float s = z / (1.f + expf(-z));
        float t = y * s; vals[i] = t; ss += t * t;
    }
#pragma unroll
    for (int o = 32; o; o >>= 1) ss += __shfl_xor(ss, o);
    __shared__ float red[4];
    if ((threadIdx.x & 63) == 0) red[threadIdx.x >> 6] = ss;
    __syncthreads();
    ss = red[0] + red[1] + red[2] + red[3];
    float sc = rsqrtf(ss / (float)DINNER + 1e-5f);
#pragma unroll
    for (int i = 0; i < 8; i++) {
        int c = threadIdx.x + i * 256;
        out[(size_t)row * DINNER + c] = f2bf(vals[i] * sc * gw[c]);
    }
}

extern "C" void kernel_launch(void* const* d_in, const int* in_sizes, int n_in,
                              void* d_out, int out_size, void* d_ws, size_t ws_size,
                              hipStream_t stream) {
    const float* x       = (const float*)d_in[0];
    const float* W_in    = (const float*)d_in[1];
    const float* conv_w  = (const float*)d_in[2];
    const float* conv_b  = (const float*)d_in[3];
    const float* dt_bias = (const float*)d_in[4];
    const float* A_log   = (const float*)d_in[5];
    const float* Dv      = (const float*)d_in[6];
    const float* norm_w  = (const float*)d_in[7];
    const float* gnorm_w = (const float*)d_in[8];
    const float* W_out   = (const float*)d_in[9];
    float* out = (float*)d_out;

    char* ws = (char*)d_ws;
    u16*   xn    = (u16*)(ws);
    u16*   W_inT = (u16*)(ws + 8388608);        // [4480][1024] bf16
    u16*   S_bf  = (u16*)(ws);                  // aliases xn/W_inT (dead by K1)
    float* cs_g  = (float*)(ws + 16777216);
    u16*   W_outT= (u16*)(ws);                  // [1024][2048] bf16, after S_bf dead
    u16*   zx    = (u16*)(ws + 17563648);       // 35,913,728 B
    u16*   xbc   = (u16*)(ws + 53477376);       // 18,874,368 B
    float* dts   = (float*)(ws + 72351744);     //    524,288 B
    u16*   yraw  = (u16*)(ws + 72876032);       // 16,777,216 B (end 89,653,248)
    u16*   cwT   = (u16*)(ws + 89653248);       //     18,432 B (end 89,671,680)
    u16*   ynorm = yraw;                        // postnorm in-place safe

    cwprep_kernel<<<(4 * CONVDIM + 255) / 256, 256, 0, stream>>>(conv_w, cwT);
    trans_kernel<<<dim3(DINPROJ_P / 64, DMODEL / 64), 256, 0, stream>>>(
        W_in, W_inT, DMODEL, DINPROJ);
    rmsnorm_in_kernel<<<NROWS, 256, 0, stream>>>(x, norm_w, xn);
    gemm128_kernel<0, DMODEL><<<(DINPROJ_P / 128) * (NROWS / 128), 256, 0, stream>>>(
        xn, W_inT, zx, nullptr, DINPROJ, DINPROJ_P / 128);
    conv_silu_kernel<<<(NROWS * NGRAN) / 256, 256, 0, stream>>>(
        zx, cwT, conv_b, dt_bias, xbc, dts);
    chunk_state_kernel<<<B_SZ * NCH * NHEADS, 256, 0, stream>>>(xbc, dts, A_log, cs_g, S_bf);
    state_pass_kernel<<<B_SZ * NHEADS, 256, 0, stream>>>(cs_g, S_bf);
    chunk_out_kernel<<<B_SZ * NCH * NHEADS, 256, 0, stream>>>(xbc, dts, cs_g, S_bf, Dv, yraw);
    trans_kernel<<<dim3(DMODEL / 64, DINNER / 64), 256, 0, stream>>>(
        W_out, W_outT, DINNER, DMODEL);
    postnorm_kernel<<<NROWS, 256, 0, stream>>>(yraw, zx, gnorm_w, ynorm);
    gemm128x64_kernel<DINNER><<<(DMODEL / 64) * (NROWS / 128), 256, 0, stream>>>(
        ynorm, W_outT, out, x, DMODEL, DMODEL / 64);
}

// Round 8
// 302.474 us; speedup vs baseline: 1.1585x; 1.0206x over previous
//
#include <hip/hip_runtime.h>
#include <hip/hip_bf16.h>

typedef unsigned short u16;
typedef unsigned int u32;
typedef u16 u16x8 __attribute__((ext_vector_type(8)));
typedef __bf16 bf16x8 __attribute__((ext_vector_type(8)));
typedef float f32x4 __attribute__((ext_vector_type(4)));

#define B_SZ 2
#define T_SZ 2048
#define DMODEL 1024
#define DINNER 2048
#define DSTATE 128
#define NHEADS 32
#define HEADDIM 64
#define CONVDIM 2304
#define DINPROJ 4384
#define DINPROJ_P 4480        // padded to 35*128 for GEMM1 tiles
#define NROWS (B_SZ * T_SZ)   // 4096
#define L_CH 128
#define NCH 16                // chunks per batch (T/L)

__device__ __forceinline__ float bf2f(u16 u) {
    union { float f; u32 i; } v; v.i = ((u32)u) << 16; return v.f;
}
__device__ __forceinline__ u16 f2bf(float f) {
    union { float f; u32 i; } v; v.f = f;
    u32 r = v.i + 0x7FFFu + ((v.i >> 16) & 1u);
    return (u16)(r >> 16);
}
__device__ __forceinline__ bf16x8 ldfrag(const u16* p) {
    return __builtin_bit_cast(bf16x8, *(const u16x8*)p);
}
__device__ __forceinline__ void gload_lds16(const u16* g, u16* l) {
    __builtin_amdgcn_global_load_lds(
        (const __attribute__((address_space(1))) unsigned int*)g,
        (__attribute__((address_space(3))) unsigned int*)l, 16, 0, 0);
}

// ---------------- transpose + f32->bf16: out[n][k] = in[k][n] ----------------
__global__ __launch_bounds__(256) void trans_kernel(
    const float* __restrict__ in, u16* __restrict__ out, int K, int N)
{
    __shared__ u16 tile[64][66];
    const int n0 = blockIdx.x * 64, k0 = blockIdx.y * 64;
    const int tid = threadIdx.x;
#pragma unroll
    for (int r = 0; r < 16; r++) {
        int idx = r * 256 + tid;
        int k = idx >> 6, n = idx & 63;
        float v = (n0 + n < N) ? in[(size_t)(k0 + k) * N + n0 + n] : 0.f;
        tile[n][k] = f2bf(v);
    }
    __syncthreads();
#pragma unroll
    for (int r = 0; r < 16; r++) {
        int idx = r * 256 + tid;
        int n = idx >> 6, k = idx & 63;
        out[(size_t)(n0 + n) * K + k0 + k] = tile[n][k];
    }
}

// ---------------- conv weight repack: cwT[k][c] = bf16(cw[c][k]) ----------------
__global__ __launch_bounds__(256) void cwprep_kernel(
    const float* __restrict__ cw, u16* __restrict__ cwT)
{
    int idx = blockIdx.x * 256 + threadIdx.x;   // over 4*CONVDIM
    if (idx < 4 * CONVDIM) {
        int k = idx / CONVDIM, c = idx - k * CONVDIM;
        cwT[idx] = f2bf(cw[c * 4 + k]);
    }
}

// ---------------- RMSNorm on input (D=1024), f32 in -> bf16 out ----------------
__global__ __launch_bounds__(256) void rmsnorm_in_kernel(
    const float* __restrict__ x, const float* __restrict__ w, u16* __restrict__ out)
{
    const int row = blockIdx.x;
    const float* xr = x + (size_t)row * DMODEL;
    float vals[4]; float ss = 0.f;
#pragma unroll
    for (int i = 0; i < 4; i++) {
        int c = threadIdx.x + i * 256;
        float v = xr[c]; vals[i] = v; ss += v * v;
    }
#pragma unroll
    for (int o = 32; o; o >>= 1) ss += __shfl_xor(ss, o);
    __shared__ float red[4];
    if ((threadIdx.x & 63) == 0) red[threadIdx.x >> 6] = ss;
    __syncthreads();
    ss = red[0] + red[1] + red[2] + red[3];
    float sc = rsqrtf(ss / (float)DMODEL + 1e-5f);
#pragma unroll
    for (int i = 0; i < 4; i++) {
        int c = threadIdx.x + i * 256;
        out[(size_t)row * DMODEL + c] = f2bf(vals[i] * sc * w[c]);
    }
}

// ---------------- 128x128 bf16 MFMA GEMM, BK=64, XOR-swizzled, compile-time K ----------------
template<int MODE, int KC>
__global__ __launch_bounds__(256) void gemm128_kernel(
    const u16* __restrict__ A, const u16* __restrict__ BT, void* __restrict__ Cv,
    const float* __restrict__ Res, int Nst, int nbx)
{
    __shared__ u16 As[128 * 64];
    __shared__ u16 Bs[128 * 64];
    const int tid = threadIdx.x;
    const int l = tid & 63, w = tid >> 6;
    const int per = nbx * 8;
    const int grp = blockIdx.x / per, r = blockIdx.x % per;
    const int m0 = (grp * 8 + (r & 7)) * 128;
    const int n0 = (r >> 3) * 128;
    const int ml = l & 15, quad = l >> 4;
    const int wm = (w & 1) * 64, wn = (w >> 1) * 64;
    f32x4 acc[4][4] = {};
    const int srow = l >> 3;
    const int sgx = (l & 7) ^ srow;
    const u16* Ag = A + (size_t)(m0 + w * 8 + srow) * KC + sgx * 8;
    const u16* Bg = BT + (size_t)(n0 + w * 8 + srow) * KC + sgx * 8;
    u16* const As_w = &As[(w * 8) * 64];
    u16* const Bs_w = &Bs[(w * 8) * 64];

#pragma unroll 4
    for (int k0 = 0; k0 < KC; k0 += 64) {
        __syncthreads();
#pragma unroll
        for (int j = 0; j < 4; j++) {
            gload_lds16(Ag + (size_t)(j * 32) * KC + k0, As_w + j * 32 * 64);
            gload_lds16(Bg + (size_t)(j * 32) * KC + k0, Bs_w + j * 32 * 64);
        }
        __syncthreads();
#pragma unroll
        for (int ks4 = 0; ks4 < 2; ks4++) {
            bf16x8 af[4], bfr[4];
#pragma unroll
            for (int i = 0; i < 4; i++)
                af[i] = ldfrag(&As[(wm + i * 16 + ml) * 64 +
                                   (((ks4 * 4 + quad) ^ (ml & 7)) * 8)]);
#pragma unroll
            for (int i = 0; i < 4; i++)
                bfr[i] = ldfrag(&Bs[(wn + i * 16 + ml) * 64 +
                                    (((ks4 * 4 + quad) ^ (ml & 7)) * 8)]);
#pragma unroll
            for (int mt = 0; mt < 4; mt++)
#pragma unroll
                for (int nt = 0; nt < 4; nt++)
                    acc[mt][nt] = __builtin_amdgcn_mfma_f32_16x16x32_bf16(
                        af[mt], bfr[nt], acc[mt][nt], 0, 0, 0);
        }
    }
#pragma unroll
    for (int mt = 0; mt < 4; mt++)
#pragma unroll
        for (int nt = 0; nt < 4; nt++)
#pragma unroll
            for (int rg = 0; rg < 4; rg++) {
                int m = m0 + wm + mt * 16 + quad * 4 + rg;
                int n = n0 + wn + nt * 16 + ml;
                if (n < Nst) {
                    if (MODE == 0)
                        ((u16*)Cv)[(size_t)m * Nst + n] = f2bf(acc[mt][nt][rg]);
                    else
                        ((float*)Cv)[(size_t)m * Nst + n] =
                            acc[mt][nt][rg] + Res[(size_t)m * Nst + n];
                }
            }
}

// ---------------- 128(M)x64(N) bf16 MFMA GEMM, BK=64, swizzled, compile-time K ----------------
template<int KC>
__global__ __launch_bounds__(256) void gemm128x64_kernel(
    const u16* __restrict__ A, const u16* __restrict__ BT, float* __restrict__ C,
    const float* __restrict__ Res, int Nst, int nbx)
{
    __shared__ u16 As[128 * 64];
    __shared__ u16 Bs[64 * 64];
    const int tid = threadIdx.x;
    const int l = tid & 63, w = tid >> 6;
    const int per = nbx * 8;
    const int grp = blockIdx.x / per, r = blockIdx.x % per;
    const int m0 = (grp * 8 + (r & 7)) * 128;
    const int n0 = (r >> 3) * 64;
    const int ml = l & 15, quad = l >> 4;
    const int wm = w * 32;
    f32x4 acc[2][4] = {};
    const int srow = l >> 3;
    const int sgx = (l & 7) ^ srow;
    const u16* Ag = A + (size_t)(m0 + w * 8 + srow) * KC + sgx * 8;
    const u16* Bg = BT + (size_t)(n0 + w * 8 + srow) * KC + sgx * 8;
    u16* const As_w = &As[(w * 8) * 64];
    u16* const Bs_w = &Bs[(w * 8) * 64];

#pragma unroll 4
    for (int k0 = 0; k0 < KC; k0 += 64) {
        __syncthreads();
#pragma unroll
        for (int j = 0; j < 4; j++)
            gload_lds16(Ag + (size_t)(j * 32) * KC + k0, As_w + j * 32 * 64);
#pragma unroll
        for (int j = 0; j < 2; j++)
            gload_lds16(Bg + (size_t)(j * 32) * KC + k0, Bs_w + j * 32 * 64);
        __syncthreads();
#pragma unroll
        for (int ks4 = 0; ks4 < 2; ks4++) {
            bf16x8 af[2], bfr[4];
#pragma unroll
            for (int i = 0; i < 2; i++)
                af[i] = ldfrag(&As[(wm + i * 16 + ml) * 64 +
                                   (((ks4 * 4 + quad) ^ (ml & 7)) * 8)]);
#pragma unroll
            for (int i = 0; i < 4; i++)
                bfr[i] = ldfrag(&Bs[(i * 16 + ml) * 64 +
                                    (((ks4 * 4 + quad) ^ (ml & 7)) * 8)]);
#pragma unroll
            for (int mt = 0; mt < 2; mt++)
#pragma unroll
                for (int nt = 0; nt < 4; nt++)
                    acc[mt][nt] = __builtin_amdgcn_mfma_f32_16x16x32_bf16(
                        af[mt], bfr[nt], acc[mt][nt], 0, 0, 0);
        }
    }
#pragma unroll
    for (int mt = 0; mt < 2; mt++)
#pragma unroll
        for (int nt = 0; nt < 4; nt++)
#pragma unroll
            for (int rg = 0; rg < 4; rg++) {
                int m = m0 + wm + mt * 16 + quad * 4 + rg;
                int n = n0 + nt * 16 + ml;
                C[(size_t)m * Nst + n] = acc[mt][nt][rg] + Res[(size_t)m * Nst + n];
            }
}

// ---------------- depthwise causal conv(4) + bias + SiLU, 8-wide, coalesced weights ----------------
#define NGRAN (CONVDIM / 8)   // 288 granules of 8 channels per row
__global__ __launch_bounds__(256) void conv_silu_kernel(
    const u16* __restrict__ zx, const u16* __restrict__ cwT,
    const float* __restrict__ cb, const float* __restrict__ dt_bias,
    u16* __restrict__ out, float* __restrict__ dts)
{
    int idx = blockIdx.x * 256 + threadIdx.x;   // over NROWS*NGRAN
    if (idx < B_SZ * NHEADS * T_SZ) {           // fused softplus(dt)
        int t = idx & (T_SZ - 1);
        int bh = idx >> 11;
        int h = bh & 31, b = bh >> 5;
        float v = bf2f(zx[(size_t)(b * T_SZ + t) * DINPROJ + (DINNER + CONVDIM) + h]) + dt_bias[h];
        float sp = (v > 20.f) ? v : log1pf(expf(v));
        dts[((size_t)bh << 11) + t] = sp;
    }
    int gr = idx % NGRAN;
    int bt = idx / NGRAN;
    int t = bt & (T_SZ - 1);
    int c0 = gr * 8;
    float acc[8];
#pragma unroll
    for (int u = 0; u < 8; u++) acc[u] = cb[c0 + u];
    const u16* base = zx + (size_t)bt * DINPROJ + DINNER + c0;
#pragma unroll
    for (int k = 0; k < 4; k++) {
        int tt = t - 3 + k;
        if (tt >= 0) {
            u16x8 xv = *(const u16x8*)(base + (ptrdiff_t)(k - 3) * DINPROJ);
            u16x8 wv = *(const u16x8*)&cwT[k * CONVDIM + c0];
#pragma unroll
            for (int u = 0; u < 8; u++)
                acc[u] += bf2f(xv[u]) * bf2f(wv[u]);
        }
    }
    u16 res[8];
#pragma unroll
    for (int u = 0; u < 8; u++) {
        float s = acc[u] / (1.f + expf(-acc[u]));
        res[u] = f2bf(s);
    }
    *(u16x8*)&out[(size_t)bt * CONVDIM + c0] = *(u16x8*)res;
}

// ---------------- K1: per-chunk cumsum + chunk-local state S = Xw^T @ B ----------------
__global__ __launch_bounds__(256) void chunk_state_kernel(
    const u16* __restrict__ xbc, const float* __restrict__ dts_g,
    const float* __restrict__ A_log, float* __restrict__ cs_g, u16* __restrict__ S_bf)
{
    const int g = blockIdx.x;
    const int b = g >> 9, rem = g & 511, c = rem >> 5, h = rem & 31;
    const int tid = threadIdx.x;
    __shared__ float tmp[128], dt_l[128], d2e[128];
    __shared__ u16 Xw[64][136];
    __shared__ u16 BsT[128][136];
    const float A = -__expf(A_log[h]);
    if (tid < 128) {
        float d = dts_g[(((size_t)(b * 32 + h)) << 11) + (c << 7) + tid];
        dt_l[tid] = d; tmp[tid] = d * A;
    }
    __syncthreads();
    for (int off = 1; off < 128; off <<= 1) {
        float add = 0.f;
        if (tid < 128 && tid >= off) add = tmp[tid - off];
        __syncthreads();
        if (tid < 128) tmp[tid] += add;
        __syncthreads();
    }
    if (tid < 128) {
        float cs = tmp[tid];
        cs_g[(((size_t)(b * 32 + h)) << 11) + (c << 7) + tid] = cs;
        d2e[tid] = __expf(tmp[127] - cs) * dt_l[tid];
    }
    __syncthreads();
    const size_t rowbase = ((size_t)(b * T_SZ + c * L_CH)) * CONVDIM;
#pragma unroll
    for (int r = 0; r < 4; r++) {
        int v = tid + r * 256;
        int t = v >> 3, p0 = (v & 7) << 3;
        u16x8 xv = *(const u16x8*)&xbc[rowbase + (size_t)t * CONVDIM + h * 64 + p0];
        float s = d2e[t];
#pragma unroll
        for (int u = 0; u < 8; u++) Xw[p0 + u][t] = f2bf(bf2f(xv[u]) * s);
    }
#pragma unroll
    for (int r = 0; r < 8; r++) {
        int v = tid + r * 256;
        int t = v >> 4, n0 = (v & 15) << 3;
        u16x8 bv = *(const u16x8*)&xbc[rowbase + (size_t)t * CONVDIM + DINNER + n0];
#pragma unroll
        for (int u = 0; u < 8; u++) BsT[n0 + u][t] = bv[u];
    }
    __syncthreads();
    const int lane = tid & 63, wv = tid >> 6, ml = lane & 15, quad = lane >> 4;
    f32x4 acc[8] = {};
    for (int k0 = 0; k0 < 128; k0 += 32) {
        bf16x8 af = ldfrag(&Xw[wv * 16 + ml][k0 + quad * 8]);
#pragma unroll
        for (int nt = 0; nt < 8; nt++) {
            bf16x8 bf = ldfrag(&BsT[nt * 16 + ml][k0 + quad * 8]);
            acc[nt] = __builtin_amdgcn_mfma_f32_16x16x32_bf16(af, bf, acc[nt], 0, 0, 0);
        }
    }
    const size_t base = (size_t)g * 8192;
#pragma unroll
    for (int nt = 0; nt < 8; nt++) {
#pragma unroll
        for (int rg = 0; rg < 4; rg++) {
            int p = wv * 16 + quad * 4 + rg, n = nt * 16 + ml;
            S_bf[base + p * 128 + n] = f2bf(acc[nt][rg]);
        }
    }
}

// ---------------- K2: inter-chunk recurrence, in-place ----------------
__global__ __launch_bounds__(256) void state_pass_kernel(
    const float* __restrict__ cs_g, u16* __restrict__ S_bf)
{
    const int bh = blockIdx.x, b = bh >> 5, h = bh & 31;
    const int tid = threadIdx.x;
    float H[32];
#pragma unroll
    for (int i = 0; i < 32; i++) H[i] = 0.f;
    for (int c = 0; c < NCH; c++) {
        float decay = __expf(cs_g[(((size_t)(b * 32 + h)) << 11) + (c << 7) + 127]);
        size_t slot = ((size_t)((b * NCH + c) * 32 + h)) * 8192 + tid * 32;
        u16 tv[32];
#pragma unroll
        for (int q = 0; q < 4; q++)
            *(u16x8*)&tv[q * 8] = *(const u16x8*)&S_bf[slot + q * 8];
        u16 hw[32];
#pragma unroll
        for (int i = 0; i < 32; i++) hw[i] = f2bf(H[i]);
#pragma unroll
        for (int q = 0; q < 4; q++)
            *(u16x8*)&S_bf[slot + q * 8] = *(const u16x8*)&hw[q * 8];
#pragma unroll
        for (int i = 0; i < 32; i++) H[i] = H[i] * decay + bf2f(tv[i]);
    }
}

// ---------------- K3: chunk output (A/B fragments direct from global; low LDS) ----------------
__global__ __launch_bounds__(256) void chunk_out_kernel(
    const u16* __restrict__ xbc, const float* __restrict__ dts_g,
    const float* __restrict__ cs_g, const u16* __restrict__ H_bf,
    const float* __restrict__ Dv, u16* __restrict__ yraw)
{
    const int g = blockIdx.x;
    const int b = g >> 9, rem = g & 511, c = rem >> 5, h = rem & 31;
    const int tid = threadIdx.x;
    __shared__ u16 Xs[64][136];     // X^T [p][t] (true transpose, must stage)
    __shared__ u16 Gs[128][40];     // masked P tile, wave-private rows
    __shared__ float cs_l[128], P_l[128], dt_l[128];
    const size_t rowbase = ((size_t)(b * T_SZ + c * L_CH)) * CONVDIM;
    const u16* Cg = xbc + rowbase + DINNER + 128;   // C rows: [t][n] pitch CONVDIM
    const u16* Bg = xbc + rowbase + DINNER;         // B rows: [t][n] pitch CONVDIM
    const u16* Hg = H_bf + (size_t)g * 8192;        // H: [p][n] pitch 128
    if (tid < 128) {
        float cs = cs_g[(((size_t)(b * 32 + h)) << 11) + (c << 7) + tid];
        cs_l[tid] = cs; P_l[tid] = __expf(cs);
        dt_l[tid] = dts_g[(((size_t)(b * 32 + h)) << 11) + (c << 7) + tid];
    }
#pragma unroll
    for (int r = 0; r < 4; r++) {
        int v = tid + r * 256; int t = v >> 3, p0 = (v & 7) << 3;
        u16x8 xv = *(const u16x8*)&xbc[rowbase + (size_t)t * CONVDIM + h * 64 + p0];
#pragma unroll
        for (int u = 0; u < 8; u++) Xs[p0 + u][t] = xv[u];
    }
    __syncthreads();
    const int lane = tid & 63, wv = tid >> 6, ml = lane & 15, quad = lane >> 4;
    const int trow = wv * 32;
    f32x4 accY[2][4] = {};
    // inter-chunk: accY = C @ H^T  (A from global C rows, B from global H rows)
    for (int k0 = 0; k0 < 128; k0 += 32) {
        bf16x8 af0 = ldfrag(Cg + (size_t)(trow + ml) * CONVDIM + k0 + quad * 8);
        bf16x8 af1 = ldfrag(Cg + (size_t)(trow + 16 + ml) * CONVDIM + k0 + quad * 8);
#pragma unroll
        for (int pt = 0; pt < 4; pt++) {
            bf16x8 bf = ldfrag(Hg + (pt * 16 + ml) * 128 + k0 + quad * 8);
            accY[0][pt] = __builtin_amdgcn_mfma_f32_16x16x32_bf16(af0, bf, accY[0][pt], 0, 0, 0);
            accY[1][pt] = __builtin_amdgcn_mfma_f32_16x16x32_bf16(af1, bf, accY[1][pt], 0, 0, 0);
        }
    }
#pragma unroll
    for (int mt = 0; mt < 2; mt++) {
#pragma unroll
        for (int rg = 0; rg < 4; rg++) {
            float pp = P_l[trow + mt * 16 + quad * 4 + rg];
#pragma unroll
            for (int pt = 0; pt < 4; pt++) accY[mt][pt][rg] *= pp;
        }
    }
    // intra-chunk in 4 j-strips of 32
    for (int js = 0; js < 4; js++) {
        const int j0 = js * 32;
        f32x4 Ga[2][2] = {};
        for (int k0 = 0; k0 < 128; k0 += 32) {
            bf16x8 af0 = ldfrag(Cg + (size_t)(trow + ml) * CONVDIM + k0 + quad * 8);
            bf16x8 af1 = ldfrag(Cg + (size_t)(trow + 16 + ml) * CONVDIM + k0 + quad * 8);
            bf16x8 bf0 = ldfrag(Bg + (size_t)(j0 + ml) * CONVDIM + k0 + quad * 8);
            bf16x8 bf1 = ldfrag(Bg + (size_t)(j0 + 16 + ml) * CONVDIM + k0 + quad * 8);
            Ga[0][0] = __builtin_amdgcn_mfma_f32_16x16x32_bf16(af0, bf0, Ga[0][0], 0, 0, 0);
            Ga[0][1] = __builtin_amdgcn_mfma_f32_16x16x32_bf16(af0, bf1, Ga[0][1], 0, 0, 0);
            Ga[1][0] = __builtin_amdgcn_mfma_f32_16x16x32_bf16(af1, bf0, Ga[1][0], 0, 0, 0);
            Ga[1][1] = __builtin_amdgcn_mfma_f32_16x16x32_bf16(af1, bf1, Ga[1][1], 0, 0, 0);
        }
        // mask + scale -> Gs (wave-private rows, no barrier needed)
#pragma unroll
        for (int mt = 0; mt < 2; mt++) {
#pragma unroll
            for (int jt = 0; jt < 2; jt++) {
#pragma unroll
                for (int rg = 0; rg < 4; rg++) {
                    int t = trow + mt * 16 + quad * 4 + rg;
                    int j = j0 + jt * 16 + ml;
                    float val = 0.f;
                    if (t >= j) val = Ga[mt][jt][rg] * __expf(cs_l[t] - cs_l[j]) * dt_l[j];
                    Gs[t][jt * 16 + ml] = f2bf(val);
                }
            }
        }
        // accY += Gs @ X  (K = 32; B-operand from Xs LDS)
#pragma unroll
        for (int mt = 0; mt < 2; mt++) {
            bf16x8 af = ldfrag(&Gs[trow + mt * 16 + ml][quad * 8]);
#pragma unroll
            for (int pt = 0; pt < 4; pt++) {
                bf16x8 bf = ldfrag(&Xs[pt * 16 + ml][j0 + quad * 8]);
                accY[mt][pt] = __builtin_amdgcn_mfma_f32_16x16x32_bf16(af, bf, accY[mt][pt], 0, 0, 0);
            }
        }
    }
    const float Dh = Dv[h];
    const size_t ybase = ((size_t)(b * T_SZ + c * L_CH)) * DINNER;
#pragma unroll
    for (int mt = 0; mt < 2; mt++) {
#pragma unroll
        for (int pt = 0; pt < 4; pt++) {
#pragma unroll
            for (int rg = 0; rg < 4; rg++) {
                int t = trow + mt * 16 + quad * 4 + rg;
                int p = pt * 16 + ml;
                float v = accY[mt][pt][rg] + Dh * bf2f(Xs[p][t]);
                yraw[ybase + (size_t)t * DINNER + h * 64 + p] = f2bf(v);
            }
        }
    }
}

// ---------------- y = rmsnorm(yraw * silu(z)) * gnorm_w (D=2048) ----------------
__global__ __launch_bounds__(256) void postnorm_kernel(
    const u16* __restrict__ yraw, const u16* __restrict__ zx,
    const float* __restrict__ gw, u16* __restrict__ out)
{
    const int row = blockIdx.x;
    const u16* yr = yraw + (size_t)row * DINNER;
    const u16* zr = zx + (size_t)row * DINPROJ;
    float vals[8]; float ss = 0.f;
#pragma unroll
    for (int i = 0; i < 8; i++) {
        int c = threadIdx.x + i * 256;
        float y = bf2f(yr[c]);
        float z = bf2f(zr[c]);
        float s = z / (1.f + expf(-z));
        float t = y * s; vals[i] = t; ss += t * t;
    }
#pragma unroll
    for (int o = 32; o; o >>= 1) ss += __shfl_xor(ss, o);
    __shared__ float red[4];
    if ((threadIdx.x & 63) == 0) red[threadIdx.x >> 6] = ss;
    __syncthreads();
    ss = red[0] + red[1] + red[2] + red[3];
    float sc = rsqrtf(ss / (float)DINNER + 1e-5f);
#pragma unroll
    for (int i = 0; i < 8; i++) {
        int c = threadIdx.x + i * 256;
        out[(size_t)row * DINNER + c] = f2bf(vals[i] * sc * gw[c]);
    }
}

extern "C" void kernel_launch(void* const* d_in, const int* in_sizes, int n_in,
                              void* d_out, int out_size, void* d_ws, size_t ws_size,
                              hipStream_t stream) {
    const float* x       = (const float*)d_in[0];
    const float* W_in    = (const float*)d_in[1];
    const float* conv_w  = (const float*)d_in[2];
    const float* conv_b  = (const float*)d_in[3];
    const float* dt_bias = (const float*)d_in[4];
    const float* A_log   = (const float*)d_in[5];
    const float* Dv      = (const float*)d_in[6];
    const float* norm_w  = (const float*)d_in[7];
    const float* gnorm_w = (const float*)d_in[8];
    const float* W_out   = (const float*)d_in[9];
    float* out = (float*)d_out;

    char* ws = (char*)d_ws;
    u16*   xn    = (u16*)(ws);
    u16*   W_inT = (u16*)(ws + 8388608);        // [4480][1024] bf16
    u16*   S_bf  = (u16*)(ws);                  // aliases xn/W_inT (dead by K1)
    float* cs_g  = (float*)(ws + 16777216);
    u16*   W_outT= (u16*)(ws);                  // [1024][2048] bf16, after S_bf dead
    u16*   zx    = (u16*)(ws + 17563648);       // 35,913,728 B
    u16*   xbc   = (u16*)(ws + 53477376);       // 18,874,368 B
    float* dts   = (float*)(ws + 72351744);     //    524,288 B
    u16*   yraw  = (u16*)(ws + 72876032);       // 16,777,216 B (end 89,653,248)
    u16*   cwT   = (u16*)(ws + 89653248);       //     18,432 B (end 89,671,680)
    u16*   ynorm = yraw;                        // postnorm in-place safe

    cwprep_kernel<<<(4 * CONVDIM + 255) / 256, 256, 0, stream>>>(conv_w, cwT);
    trans_kernel<<<dim3(DINPROJ_P / 64, DMODEL / 64), 256, 0, stream>>>(
        W_in, W_inT, DMODEL, DINPROJ);
    rmsnorm_in_kernel<<<NROWS, 256, 0, stream>>>(x, norm_w, xn);
    gemm128_kernel<0, DMODEL><<<(DINPROJ_P / 128) * (NROWS / 128), 256, 0, stream>>>(
        xn, W_inT, zx, nullptr, DINPROJ, DINPROJ_P / 128);
    conv_silu_kernel<<<(NROWS * NGRAN) / 256, 256, 0, stream>>>(
        zx, cwT, conv_b, dt_bias, xbc, dts);
    chunk_state_kernel<<<B_SZ * NCH * NHEADS, 256, 0, stream>>>(xbc, dts, A_log, cs_g, S_bf);
    state_pass_kernel<<<B_SZ * NHEADS, 256, 0, stream>>>(cs_g, S_bf);
    chunk_out_kernel<<<B_SZ * NCH * NHEADS, 256, 0, stream>>>(xbc, dts, cs_g, S_bf, Dv, yraw);
    trans_kernel<<<dim3(DMODEL / 64, DINNER / 64), 256, 0, stream>>>(
        W_out, W_outT, DINNER, DMODEL);
    postnorm_kernel<<<NROWS, 256, 0, stream>>>(yraw, zx, gnorm_w, ynorm);
    gemm128x64_kernel<DINNER><<<(DMODEL / 64) * (NROWS / 128), 256, 0, stream>>>(
        ynorm, W_outT, out, x, DMODEL, DMODEL / 64);
}

// Round 9
// 297.795 us; speedup vs baseline: 1.1767x; 1.0157x over previous
//
#include <hip/hip_runtime.h>
#include <hip/hip_bf16.h>

typedef unsigned short u16;
typedef unsigned int u32;
typedef u16 u16x8 __attribute__((ext_vector_type(8)));
typedef __bf16 bf16x8 __attribute__((ext_vector_type(8)));
typedef float f32x4 __attribute__((ext_vector_type(4)));

#define B_SZ 2
#define T_SZ 2048
#define DMODEL 1024
#define DINNER 2048
#define DSTATE 128
#define NHEADS 32
#define HEADDIM 64
#define CONVDIM 2304
#define DINPROJ 4384
#define DINPROJ_P 4480        // padded to 35*128 for GEMM1 tiles
#define NROWS (B_SZ * T_SZ)   // 4096
#define L_CH 128
#define NCH 16                // chunks per batch (T/L)

__device__ __forceinline__ float bf2f(u16 u) {
    union { float f; u32 i; } v; v.i = ((u32)u) << 16; return v.f;
}
__device__ __forceinline__ u16 f2bf(float f) {
    union { float f; u32 i; } v; v.f = f;
    u32 r = v.i + 0x7FFFu + ((v.i >> 16) & 1u);
    return (u16)(r >> 16);
}
__device__ __forceinline__ bf16x8 ldfrag(const u16* p) {
    return __builtin_bit_cast(bf16x8, *(const u16x8*)p);
}
__device__ __forceinline__ void gload_lds16(const u16* g, u16* l) {
    __builtin_amdgcn_global_load_lds(
        (const __attribute__((address_space(1))) unsigned int*)g,
        (__attribute__((address_space(3))) unsigned int*)l, 16, 0, 0);
}

// ---------------- fused prologue: trans(W_in) | trans(W_out) | rmsnorm(x) | cwprep ----------------
// blocks [0,1120): W_in transpose (70 x 16 tiles of 64x64)
// blocks [1120,1632): W_out transpose (16 x 32 tiles)
// blocks [1632,5728): rmsnorm rows
// block 5728: conv weight repack
__device__ void trans_tile(const float* __restrict__ in, u16* __restrict__ out,
                           int K, int N, int n0, int k0)
{
    __shared__ u16 tile[64][66];
    const int tid = threadIdx.x;
#pragma unroll
    for (int r = 0; r < 16; r++) {
        int idx = r * 256 + tid;
        int k = idx >> 6, n = idx & 63;
        float v = (n0 + n < N) ? in[(size_t)(k0 + k) * N + n0 + n] : 0.f;
        tile[n][k] = f2bf(v);
    }
    __syncthreads();
#pragma unroll
    for (int r = 0; r < 16; r++) {
        int idx = r * 256 + tid;
        int n = idx >> 6, k = idx & 63;
        out[(size_t)(n0 + n) * K + k0 + k] = tile[n][k];
    }
}

__global__ __launch_bounds__(256) void prep_kernel(
    const float* __restrict__ W_in, u16* __restrict__ W_inT,
    const float* __restrict__ W_out, u16* __restrict__ W_outT,
    const float* __restrict__ x, const float* __restrict__ nw, u16* __restrict__ xn,
    const float* __restrict__ cw, u16* __restrict__ cwT)
{
    const int blk = blockIdx.x;
    const int tid = threadIdx.x;
    if (blk < 1120) {
        trans_tile(W_in, W_inT, DMODEL, DINPROJ, (blk % 70) * 64, (blk / 70) * 64);
    } else if (blk < 1632) {
        int idx = blk - 1120;
        trans_tile(W_out, W_outT, DINNER, DMODEL, (idx % 16) * 64, (idx / 16) * 64);
    } else if (blk < 5728) {
        const int row = blk - 1632;
        const float* xr = x + (size_t)row * DMODEL;
        float vals[4]; float ss = 0.f;
#pragma unroll
        for (int i = 0; i < 4; i++) {
            int c = tid + i * 256;
            float v = xr[c]; vals[i] = v; ss += v * v;
        }
#pragma unroll
        for (int o = 32; o; o >>= 1) ss += __shfl_xor(ss, o);
        __shared__ float red[4];
        if ((tid & 63) == 0) red[tid >> 6] = ss;
        __syncthreads();
        ss = red[0] + red[1] + red[2] + red[3];
        float sc = rsqrtf(ss / (float)DMODEL + 1e-5f);
#pragma unroll
        for (int i = 0; i < 4; i++) {
            int c = tid + i * 256;
            xn[(size_t)row * DMODEL + c] = f2bf(vals[i] * sc * nw[c]);
        }
    } else {
        for (int idx = tid; idx < 4 * CONVDIM; idx += 256) {
            int k = idx / CONVDIM, c = idx - k * CONVDIM;
            cwT[idx] = f2bf(cw[c * 4 + k]);
        }
    }
}

// ---------------- 128x128 bf16 MFMA GEMM, BK=64, XOR-swizzled, compile-time K ----------------
template<int MODE, int KC>
__global__ __launch_bounds__(256) void gemm128_kernel(
    const u16* __restrict__ A, const u16* __restrict__ BT, void* __restrict__ Cv,
    const float* __restrict__ Res, int Nst, int nbx)
{
    __shared__ u16 As[128 * 64];
    __shared__ u16 Bs[128 * 64];
    const int tid = threadIdx.x;
    const int l = tid & 63, w = tid >> 6;
    const int per = nbx * 8;
    const int grp = blockIdx.x / per, r = blockIdx.x % per;
    const int m0 = (grp * 8 + (r & 7)) * 128;
    const int n0 = (r >> 3) * 128;
    const int ml = l & 15, quad = l >> 4;
    const int wm = (w & 1) * 64, wn = (w >> 1) * 64;
    f32x4 acc[4][4] = {};
    const int srow = l >> 3;
    const int sgx = (l & 7) ^ srow;
    const u16* Ag = A + (size_t)(m0 + w * 8 + srow) * KC + sgx * 8;
    const u16* Bg = BT + (size_t)(n0 + w * 8 + srow) * KC + sgx * 8;
    u16* const As_w = &As[(w * 8) * 64];
    u16* const Bs_w = &Bs[(w * 8) * 64];

#pragma unroll 4
    for (int k0 = 0; k0 < KC; k0 += 64) {
        __syncthreads();
#pragma unroll
        for (int j = 0; j < 4; j++) {
            gload_lds16(Ag + (size_t)(j * 32) * KC + k0, As_w + j * 32 * 64);
            gload_lds16(Bg + (size_t)(j * 32) * KC + k0, Bs_w + j * 32 * 64);
        }
        __syncthreads();
#pragma unroll
        for (int ks4 = 0; ks4 < 2; ks4++) {
            bf16x8 af[4], bfr[4];
#pragma unroll
            for (int i = 0; i < 4; i++)
                af[i] = ldfrag(&As[(wm + i * 16 + ml) * 64 +
                                   (((ks4 * 4 + quad) ^ (ml & 7)) * 8)]);
#pragma unroll
            for (int i = 0; i < 4; i++)
                bfr[i] = ldfrag(&Bs[(wn + i * 16 + ml) * 64 +
                                    (((ks4 * 4 + quad) ^ (ml & 7)) * 8)]);
#pragma unroll
            for (int mt = 0; mt < 4; mt++)
#pragma unroll
                for (int nt = 0; nt < 4; nt++)
                    acc[mt][nt] = __builtin_amdgcn_mfma_f32_16x16x32_bf16(
                        af[mt], bfr[nt], acc[mt][nt], 0, 0, 0);
        }
    }
#pragma unroll
    for (int mt = 0; mt < 4; mt++)
#pragma unroll
        for (int nt = 0; nt < 4; nt++)
#pragma unroll
            for (int rg = 0; rg < 4; rg++) {
                int m = m0 + wm + mt * 16 + quad * 4 + rg;
                int n = n0 + wn + nt * 16 + ml;
                if (n < Nst) {
                    if (MODE == 0)
                        ((u16*)Cv)[(size_t)m * Nst + n] = f2bf(acc[mt][nt][rg]);
                    else
                        ((float*)Cv)[(size_t)m * Nst + n] =
                            acc[mt][nt][rg] + Res[(size_t)m * Nst + n];
                }
            }
}

// ---------------- 128(M)x64(N) bf16 MFMA GEMM, 2D grid (n fastest for A reuse) ----------------
template<int KC>
__global__ __launch_bounds__(256) void gemm128x64_kernel(
    const u16* __restrict__ A, const u16* __restrict__ BT, float* __restrict__ C,
    const float* __restrict__ Res, int Nst)
{
    __shared__ u16 As[128 * 64];
    __shared__ u16 Bs[64 * 64];
    const int tid = threadIdx.x;
    const int l = tid & 63, w = tid >> 6;
    const int m0 = blockIdx.y * 128;
    const int n0 = blockIdx.x * 64;
    const int ml = l & 15, quad = l >> 4;
    const int wm = w * 32;
    f32x4 acc[2][4] = {};
    const int srow = l >> 3;
    const int sgx = (l & 7) ^ srow;
    const u16* Ag = A + (size_t)(m0 + w * 8 + srow) * KC + sgx * 8;
    const u16* Bg = BT + (size_t)(n0 + w * 8 + srow) * KC + sgx * 8;
    u16* const As_w = &As[(w * 8) * 64];
    u16* const Bs_w = &Bs[(w * 8) * 64];

#pragma unroll 4
    for (int k0 = 0; k0 < KC; k0 += 64) {
        __syncthreads();
#pragma unroll
        for (int j = 0; j < 4; j++)
            gload_lds16(Ag + (size_t)(j * 32) * KC + k0, As_w + j * 32 * 64);
#pragma unroll
        for (int j = 0; j < 2; j++)
            gload_lds16(Bg + (size_t)(j * 32) * KC + k0, Bs_w + j * 32 * 64);
        __syncthreads();
#pragma unroll
        for (int ks4 = 0; ks4 < 2; ks4++) {
            bf16x8 af[2], bfr[4];
#pragma unroll
            for (int i = 0; i < 2; i++)
                af[i] = ldfrag(&As[(wm + i * 16 + ml) * 64 +
                                   (((ks4 * 4 + quad) ^ (ml & 7)) * 8)]);
#pragma unroll
            for (int i = 0; i < 4; i++)
                bfr[i] = ldfrag(&Bs[(i * 16 + ml) * 64 +
                                    (((ks4 * 4 + quad) ^ (ml & 7)) * 8)]);
#pragma unroll
            for (int mt = 0; mt < 2; mt++)
#pragma unroll
                for (int nt = 0; nt < 4; nt++)
                    acc[mt][nt] = __builtin_amdgcn_mfma_f32_16x16x32_bf16(
                        af[mt], bfr[nt], acc[mt][nt], 0, 0, 0);
        }
    }
#pragma unroll
    for (int mt = 0; mt < 2; mt++)
#pragma unroll
        for (int nt = 0; nt < 4; nt++)
#pragma unroll
            for (int rg = 0; rg < 4; rg++) {
                int m = m0 + wm + mt * 16 + quad * 4 + rg;
                int n = n0 + nt * 16 + ml;
                C[(size_t)m * Nst + n] = acc[mt][nt][rg] + Res[(size_t)m * Nst + n];
            }
}

// ---------------- depthwise causal conv(4) + bias + SiLU, 8-wide, coalesced weights ----------------
#define NGRAN (CONVDIM / 8)   // 288 granules of 8 channels per row
__global__ __launch_bounds__(256) void conv_silu_kernel(
    const u16* __restrict__ zx, const u16* __restrict__ cwT,
    const float* __restrict__ cb, const float* __restrict__ dt_bias,
    u16* __restrict__ out, float* __restrict__ dts)
{
    int idx = blockIdx.x * 256 + threadIdx.x;   // over NROWS*NGRAN
    if (idx < B_SZ * NHEADS * T_SZ) {           // fused softplus(dt)
        int t = idx & (T_SZ - 1);
        int bh = idx >> 11;
        int h = bh & 31, b = bh >> 5;
        float v = bf2f(zx[(size_t)(b * T_SZ + t) * DINPROJ + (DINNER + CONVDIM) + h]) + dt_bias[h];
        float sp = (v > 20.f) ? v : log1pf(expf(v));
        dts[((size_t)bh << 11) + t] = sp;
    }
    int gr = idx % NGRAN;
    int bt = idx / NGRAN;
    int t = bt & (T_SZ - 1);
    int c0 = gr * 8;
    float acc[8];
#pragma unroll
    for (int u = 0; u < 8; u++) acc[u] = cb[c0 + u];
    const u16* base = zx + (size_t)bt * DINPROJ + DINNER + c0;
#pragma unroll
    for (int k = 0; k < 4; k++) {
        int tt = t - 3 + k;
        if (tt >= 0) {
            u16x8 xv = *(const u16x8*)(base + (ptrdiff_t)(k - 3) * DINPROJ);
            u16x8 wv = *(const u16x8*)&cwT[k * CONVDIM + c0];
#pragma unroll
            for (int u = 0; u < 8; u++)
                acc[u] += bf2f(xv[u]) * bf2f(wv[u]);
        }
    }
    u16 res[8];
#pragma unroll
    for (int u = 0; u < 8; u++) {
        float s = acc[u] / (1.f + expf(-acc[u]));
        res[u] = f2bf(s);
    }
    *(u16x8*)&out[(size_t)bt * CONVDIM + c0] = *(u16x8*)res;
}

// ---------------- K1: per-chunk cumsum + chunk-local state S = Xw^T @ B ----------------
__global__ __launch_bounds__(256) void chunk_state_kernel(
    const u16* __restrict__ xbc, const float* __restrict__ dts_g,
    const float* __restrict__ A_log, float* __restrict__ cs_g, u16* __restrict__ S_bf)
{
    const int g = blockIdx.x;
    const int b = g >> 9, rem = g & 511, c = rem >> 5, h = rem & 31;
    const int tid = threadIdx.x;
    __shared__ float tmp[128], dt_l[128], d2e[128];
    __shared__ u16 Xw[64][136];
    __shared__ u16 BsT[128][136];
    const float A = -__expf(A_log[h]);
    if (tid < 128) {
        float d = dts_g[(((size_t)(b * 32 + h)) << 11) + (c << 7) + tid];
        dt_l[tid] = d; tmp[tid] = d * A;
    }
    __syncthreads();
    for (int off = 1; off < 128; off <<= 1) {
        float add = 0.f;
        if (tid < 128 && tid >= off) add = tmp[tid - off];
        __syncthreads();
        if (tid < 128) tmp[tid] += add;
        __syncthreads();
    }
    if (tid < 128) {
        float cs = tmp[tid];
        cs_g[(((size_t)(b * 32 + h)) << 11) + (c << 7) + tid] = cs;
        d2e[tid] = __expf(tmp[127] - cs) * dt_l[tid];
    }
    __syncthreads();
    const size_t rowbase = ((size_t)(b * T_SZ + c * L_CH)) * CONVDIM;
#pragma unroll
    for (int r = 0; r < 4; r++) {
        int v = tid + r * 256;
        int t = v >> 3, p0 = (v & 7) << 3;
        u16x8 xv = *(const u16x8*)&xbc[rowbase + (size_t)t * CONVDIM + h * 64 + p0];
        float s = d2e[t];
#pragma unroll
        for (int u = 0; u < 8; u++) Xw[p0 + u][t] = f2bf(bf2f(xv[u]) * s);
    }
#pragma unroll
    for (int r = 0; r < 8; r++) {
        int v = tid + r * 256;
        int t = v >> 4, n0 = (v & 15) << 3;
        u16x8 bv = *(const u16x8*)&xbc[rowbase + (size_t)t * CONVDIM + DINNER + n0];
#pragma unroll
        for (int u = 0; u < 8; u++) BsT[n0 + u][t] = bv[u];
    }
    __syncthreads();
    const int lane = tid & 63, wv = tid >> 6, ml = lane & 15, quad = lane >> 4;
    f32x4 acc[8] = {};
    for (int k0 = 0; k0 < 128; k0 += 32) {
        bf16x8 af = ldfrag(&Xw[wv * 16 + ml][k0 + quad * 8]);
#pragma unroll
        for (int nt = 0; nt < 8; nt++) {
            bf16x8 bf = ldfrag(&BsT[nt * 16 + ml][k0 + quad * 8]);
            acc[nt] = __builtin_amdgcn_mfma_f32_16x16x32_bf16(af, bf, acc[nt], 0, 0, 0);
        }
    }
    const size_t base = (size_t)g * 8192;
#pragma unroll
    for (int nt = 0; nt < 8; nt++) {
#pragma unroll
        for (int rg = 0; rg < 4; rg++) {
            int p = wv * 16 + quad * 4 + rg, n = nt * 16 + ml;
            S_bf[base + p * 128 + n] = f2bf(acc[nt][rg]);
        }
    }
}

// ---------------- K2: inter-chunk recurrence, in-place ----------------
__global__ __launch_bounds__(256) void state_pass_kernel(
    const float* __restrict__ cs_g, u16* __restrict__ S_bf)
{
    const int bh = blockIdx.x, b = bh >> 5, h = bh & 31;
    const int tid = threadIdx.x;
    float H[32];
#pragma unroll
    for (int i = 0; i < 32; i++) H[i] = 0.f;
    for (int c = 0; c < NCH; c++) {
        float decay = __expf(cs_g[(((size_t)(b * 32 + h)) << 11) + (c << 7) + 127]);
        size_t slot = ((size_t)((b * NCH + c) * 32 + h)) * 8192 + tid * 32;
        u16 tv[32];
#pragma unroll
        for (int q = 0; q < 4; q++)
            *(u16x8*)&tv[q * 8] = *(const u16x8*)&S_bf[slot + q * 8];
        u16 hw[32];
#pragma unroll
        for (int i = 0; i < 32; i++) hw[i] = f2bf(H[i]);
#pragma unroll
        for (int q = 0; q < 4; q++)
            *(u16x8*)&S_bf[slot + q * 8] = *(const u16x8*)&hw[q * 8];
#pragma unroll
        for (int i = 0; i < 32; i++) H[i] = H[i] * decay + bf2f(tv[i]);
    }
}

// ---------------- K3: chunk output (A/B fragments direct from global; low LDS) ----------------
__global__ __launch_bounds__(256) void chunk_out_kernel(
    const u16* __restrict__ xbc, const float* __restrict__ dts_g,
    const float* __restrict__ cs_g, const u16* __restrict__ H_bf,
    const float* __restrict__ Dv, u16* __restrict__ yraw)
{
    const int g = blockIdx.x;
    const int b = g >> 9, rem = g & 511, c = rem >> 5, h = rem & 31;
    const int tid = threadIdx.x;
    __shared__ u16 Xs[64][136];     // X^T [p][t]
    __shared__ u16 Gs[128][40];     // masked P tile, wave-private rows
    __shared__ float cs_l[128], P_l[128], dt_l[128];
    const size_t rowbase = ((size_t)(b * T_SZ + c * L_CH)) * CONVDIM;
    const u16* Cg = xbc + rowbase + DINNER + 128;
    const u16* Bg = xbc + rowbase + DINNER;
    const u16* Hg = H_bf + (size_t)g * 8192;
    if (tid < 128) {
        float cs = cs_g[(((size_t)(b * 32 + h)) << 11) + (c << 7) + tid];
        cs_l[tid] = cs; P_l[tid] = __expf(cs);
        dt_l[tid] = dts_g[(((size_t)(b * 32 + h)) << 11) + (c << 7) + tid];
    }
#pragma unroll
    for (int r = 0; r < 4; r++) {
        int v = tid + r * 256; int t = v >> 3, p0 = (v & 7) << 3;
        u16x8 xv = *(const u16x8*)&xbc[rowbase + (size_t)t * CONVDIM + h * 64 + p0];
#pragma unroll
        for (int u = 0; u < 8; u++) Xs[p0 + u][t] = xv[u];
    }
    __syncthreads();
    const int lane = tid & 63, wv = tid >> 6, ml = lane & 15, quad = lane >> 4;
    const int trow = wv * 32;
    f32x4 accY[2][4] = {};
    for (int k0 = 0; k0 < 128; k0 += 32) {
        bf16x8 af0 = ldfrag(Cg + (size_t)(trow + ml) * CONVDIM + k0 + quad * 8);
        bf16x8 af1 = ldfrag(Cg + (size_t)(trow + 16 + ml) * CONVDIM + k0 + quad * 8);
#pragma unroll
        for (int pt = 0; pt < 4; pt++) {
            bf16x8 bf = ldfrag(Hg + (pt * 16 + ml) * 128 + k0 + quad * 8);
            accY[0][pt] = __builtin_amdgcn_mfma_f32_16x16x32_bf16(af0, bf, accY[0][pt], 0, 0, 0);
            accY[1][pt] = __builtin_amdgcn_mfma_f32_16x16x32_bf16(af1, bf, accY[1][pt], 0, 0, 0);
        }
    }
#pragma unroll
    for (int mt = 0; mt < 2; mt++) {
#pragma unroll
        for (int rg = 0; rg < 4; rg++) {
            float pp = P_l[trow + mt * 16 + quad * 4 + rg];
#pragma unroll
            for (int pt = 0; pt < 4; pt++) accY[mt][pt][rg] *= pp;
        }
    }
    for (int js = 0; js < 4; js++) {
        const int j0 = js * 32;
        f32x4 Ga[2][2] = {};
        for (int k0 = 0; k0 < 128; k0 += 32) {
            bf16x8 af0 = ldfrag(Cg + (size_t)(trow + ml) * CONVDIM + k0 + quad * 8);
            bf16x8 af1 = ldfrag(Cg + (size_t)(trow + 16 + ml) * CONVDIM + k0 + quad * 8);
            bf16x8 bf0 = ldfrag(Bg + (size_t)(j0 + ml) * CONVDIM + k0 + quad * 8);
            bf16x8 bf1 = ldfrag(Bg + (size_t)(j0 + 16 + ml) * CONVDIM + k0 + quad * 8);
            Ga[0][0] = __builtin_amdgcn_mfma_f32_16x16x32_bf16(af0, bf0, Ga[0][0], 0, 0, 0);
            Ga[0][1] = __builtin_amdgcn_mfma_f32_16x16x32_bf16(af0, bf1, Ga[0][1], 0, 0, 0);
            Ga[1][0] = __builtin_amdgcn_mfma_f32_16x16x32_bf16(af1, bf0, Ga[1][0], 0, 0, 0);
            Ga[1][1] = __builtin_amdgcn_mfma_f32_16x16x32_bf16(af1, bf1, Ga[1][1], 0, 0, 0);
        }
#pragma unroll
        for (int mt = 0; mt < 2; mt++) {
#pragma unroll
            for (int jt = 0; jt < 2; jt++) {
#pragma unroll
                for (int rg = 0; rg < 4; rg++) {
                    int t = trow + mt * 16 + quad * 4 + rg;
                    int j = j0 + jt * 16 + ml;
                    float val = 0.f;
                    if (t >= j) val = Ga[mt][jt][rg] * __expf(cs_l[t] - cs_l[j]) * dt_l[j];
                    Gs[t][jt * 16 + ml] = f2bf(val);
                }
            }
        }
#pragma unroll
        for (int mt = 0; mt < 2; mt++) {
            bf16x8 af = ldfrag(&Gs[trow + mt * 16 + ml][quad * 8]);
#pragma unroll
            for (int pt = 0; pt < 4; pt++) {
                bf16x8 bf = ldfrag(&Xs[pt * 16 + ml][j0 + quad * 8]);
                accY[mt][pt] = __builtin_amdgcn_mfma_f32_16x16x32_bf16(af, bf, accY[mt][pt], 0, 0, 0);
            }
        }
    }
    const float Dh = Dv[h];
    const size_t ybase = ((size_t)(b * T_SZ + c * L_CH)) * DINNER;
#pragma unroll
    for (int mt = 0; mt < 2; mt++) {
#pragma unroll
        for (int pt = 0; pt < 4; pt++) {
#pragma unroll
            for (int rg = 0; rg < 4; rg++) {
                int t = trow + mt * 16 + quad * 4 + rg;
                int p = pt * 16 + ml;
                float v = accY[mt][pt][rg] + Dh * bf2f(Xs[p][t]);
                yraw[ybase + (size_t)t * DINNER + h * 64 + p] = f2bf(v);
            }
        }
    }
}

// ---------------- y = rmsnorm(yraw * silu(z)) * gnorm_w (D=2048) ----------------
__global__ __launch_bounds__(256) void postnorm_kernel(
    const u16* __restrict__ yraw, const u16* __restrict__ zx,
    const float* __restrict__ gw, u16* __restrict__ out)
{
    const int row = blockIdx.x;
    const u16* yr = yraw + (size_t)row * DINNER;
    const u16* zr = zx + (size_t)row * DINPROJ;
    float vals[8]; float ss = 0.f;
#pragma unroll
    for (int i = 0; i < 8; i++) {
        int c = threadIdx.x + i * 256;
        float y = bf2f(yr[c]);
        float z = bf2f(zr[c]);
        float s = z / (1.f + expf(-z));
        float t = y * s; vals[i] = t; ss += t * t;
    }
#pragma unroll
    for (int o = 32; o; o >>= 1) ss += __shfl_xor(ss, o);
    __shared__ float red[4];
    if ((threadIdx.x & 63) == 0) red[threadIdx.x >> 6] = ss;
    __syncthreads();
    ss = red[0] + red[1] + red[2] + red[3];
    float sc = rsqrtf(ss / (float)DINNER + 1e-5f);
#pragma unroll
    for (int i = 0; i < 8; i++) {
        int c = threadIdx.x + i * 256;
        out[(size_t)row * DINNER + c] = f2bf(vals[i] * sc * gw[c]);
    }
}

extern "C" void kernel_launch(void* const* d_in, const int* in_sizes, int n_in,
                              void* d_out, int out_size, void* d_ws, size_t ws_size,
                              hipStream_t stream) {
    const float* x       = (const float*)d_in[0];
    const float* W_in    = (const float*)d_in[1];
    const float* conv_w  = (const float*)d_in[2];
    const float* conv_b  = (const float*)d_in[3];
    const float* dt_bias = (const float*)d_in[4];
    const float* A_log   = (const float*)d_in[5];
    const float* Dv      = (const float*)d_in[6];
    const float* norm_w  = (const float*)d_in[7];
    const float* gnorm_w = (const float*)d_in[8];
    const float* W_out   = (const float*)d_in[9];
    float* out = (float*)d_out;

    char* ws = (char*)d_ws;
    u16*   xn    = (u16*)(ws);                  // [0, 8.39M)  (aliases S_bf later)
    u16*   W_inT = (u16*)(ws + 8388608);        // [4480][1024] bf16 (dead after GEMM1)
    u16*   S_bf  = (u16*)(ws);                  // 16.78M, from chunk_state on
    float* cs_g  = (float*)(ws + 16777216);
    u16*   zx    = (u16*)(ws + 17563648);       // 35,913,728 B
    u16*   xbc   = (u16*)(ws + 53477376);       // 18,874,368 B
    float* dts   = (float*)(ws + 72351744);     //    524,288 B
    u16*   yraw  = (u16*)(ws + 72876032);       // 16,777,216 B
    u16*   cwT   = (u16*)(ws + 89653248);       //     18,432 B
    u16*   W_outT= (u16*)(ws + 89671680);       //  4,194,304 B (end 93,865,984)
    u16*   ynorm = yraw;                        // postnorm in-place safe

    prep_kernel<<<5729, 256, 0, stream>>>(
        W_in, W_inT, W_out, W_outT, x, norm_w, xn, conv_w, cwT);
    gemm128_kernel<0, DMODEL><<<(DINPROJ_P / 128) * (NROWS / 128), 256, 0, stream>>>(
        xn, W_inT, zx, nullptr, DINPROJ, DINPROJ_P / 128);
    conv_silu_kernel<<<(NROWS * NGRAN) / 256, 256, 0, stream>>>(
        zx, cwT, conv_b, dt_bias, xbc, dts);
    chunk_state_kernel<<<B_SZ * NCH * NHEADS, 256, 0, stream>>>(xbc, dts, A_log, cs_g, S_bf);
    state_pass_kernel<<<B_SZ * NHEADS, 256, 0, stream>>>(cs_g, S_bf);
    chunk_out_kernel<<<B_SZ * NCH * NHEADS, 256, 0, stream>>>(xbc, dts, cs_g, S_bf, Dv, yraw);
    postnorm_kernel<<<NROWS, 256, 0, stream>>>(yraw, zx, gnorm_w, ynorm);
    gemm128x64_kernel<DINNER><<<dim3(DMODEL / 64, NROWS / 128), 256, 0, stream>>>(
        ynorm, W_outT, out, x, DMODEL);
}